// Round 1
// baseline (732.600 us; speedup 1.0000x reference)
//
#include <hip/hip_runtime.h>
#include <math.h>

#define N_NODES 50000
#define N_EDGES 1600000

// ---------------- CSR build ----------------

__global__ void hist_kernel(const int* __restrict__ dst, int* __restrict__ deg, int e) {
    int i = blockIdx.x * blockDim.x + threadIdx.x;
    if (i < e) atomicAdd(&deg[dst[i]], 1);
}

__global__ void scan_kernel(const int* __restrict__ deg, int* __restrict__ rowptr, int n) {
    __shared__ int sdata[1024];
    __shared__ int carry;
    if (threadIdx.x == 0) carry = 0;
    __syncthreads();
    for (int base = 0; base < n; base += 1024) {
        int i = base + threadIdx.x;
        int v = (i < n) ? deg[i] : 0;
        sdata[threadIdx.x] = v;
        __syncthreads();
        for (int off = 1; off < 1024; off <<= 1) {
            int t = (threadIdx.x >= off) ? sdata[threadIdx.x - off] : 0;
            __syncthreads();
            sdata[threadIdx.x] += t;
            __syncthreads();
        }
        if (i < n) rowptr[i] = carry + sdata[threadIdx.x] - v;   // exclusive
        __syncthreads();
        if (threadIdx.x == 1023) carry += sdata[1023];
        __syncthreads();
    }
    if (threadIdx.x == 0) rowptr[n] = carry;
}

__global__ void scatter_kernel(const int* __restrict__ src, const int* __restrict__ dst,
                               const int* __restrict__ rowptr, int* __restrict__ cursor,
                               int* __restrict__ csr_src, int e) {
    int i = blockIdx.x * blockDim.x + threadIdx.x;
    if (i < e) {
        int d = dst[i];
        int p = atomicAdd(&cursor[d], 1);
        csr_src[rowptr[d] + p] = src[i];
    }
}

// ---------------- h = in @ W ; as = h.a_src ; ad = h.a_dst ----------------
// One group of C lanes per row; block = 256 threads = 256/C rows.

template<int K, int C>
__global__ __launch_bounds__(256) void gemm_alpha(
        const float* __restrict__ in, const float* __restrict__ W,
        const float* __restrict__ a_src, const float* __restrict__ a_dst,
        float* __restrict__ h, float* __restrict__ as_, float* __restrict__ ad_, int n)
{
    constexpr int ROWS = 256 / C;
    __shared__ float sx[ROWS * K];
    int row0 = blockIdx.x * ROWS;
    for (int idx = threadIdx.x; idx < ROWS * K; idx += 256) {
        int r = idx / K, k = idx % K;
        int ni = row0 + r;
        sx[idx] = (ni < n) ? in[ni * K + k] : 0.f;
    }
    __syncthreads();
    int g = threadIdx.x / C;
    int c = threadIdx.x % C;
    int ni = row0 + g;
    const float* xr = &sx[g * K];
    float acc = 0.f;
#pragma unroll 8
    for (int k = 0; k < K; ++k) acc += xr[k] * W[k * C + c];
    float vs = acc * a_src[c];
    float vd = acc * a_dst[c];
#pragma unroll
    for (int msk = 1; msk < C; msk <<= 1) {
        vs += __shfl_xor(vs, msk);
        vd += __shfl_xor(vd, msk);
    }
    if (ni < n) {
        h[ni * C + c] = acc;
        if (c == 0) { as_[ni] = vs; ad_[ni] = vd; }
    }
}

// ---------------- per-dst softmax + weighted aggregation ----------------
// One 64-lane wave per dst node. CSR has incoming edges grouped by dst.

__device__ __forceinline__ float leaky(float e) {
    return (e >= 0.f) ? e : 0.2f * e;
}

template<int C, bool RELU>
__global__ __launch_bounds__(256) void agg_kernel(
        const float* __restrict__ h, const float* __restrict__ as_, const float* __restrict__ ad_,
        const int* __restrict__ rowptr, const int* __restrict__ csr_src,
        const float* __restrict__ bias, float* __restrict__ out, int n)
{
    int wave = (blockIdx.x * blockDim.x + threadIdx.x) >> 6;
    int lane = threadIdx.x & 63;
    if (wave >= n) return;
    int start = rowptr[wave], end = rowptr[wave + 1];
    float adn = ad_[wave];

    // phase A: segment max (lane-parallel over edges)
    float m = -3.402823466e38f;
    for (int i = start + lane; i < end; i += 64) {
        float e = leaky(as_[csr_src[i]] + adn);
        m = fmaxf(m, e);
    }
#pragma unroll
    for (int off = 32; off; off >>= 1) m = fmaxf(m, __shfl_xor(m, off));

    // phase B: denom = sum exp(e - m)
    float sum = 0.f;
    for (int i = start + lane; i < end; i += 64) {
        float e = leaky(as_[csr_src[i]] + adn);
        sum += __expf(e - m);
    }
#pragma unroll
    for (int off = 32; off; off >>= 1) sum += __shfl_xor(sum, off);
    float inv = 1.f / (sum + 1e-16f);

    // phase C: out[n][c] = sum_e alpha_e * h[src_e][c]
    if constexpr (C == 64) {
        float acc = 0.f;
        for (int t = start; t < end; ++t) {
            int s = csr_src[t];                         // broadcast load
            float alpha = __expf(leaky(as_[s] + adn) - m) * inv;
            acc = fmaf(alpha, h[s * 64 + lane], acc);   // coalesced 256B
        }
        float o = acc + bias[lane];
        if (RELU) o = fmaxf(o, 0.f);
        out[wave * 64 + lane] = o;
    } else {  // C == 16: 4 edges in parallel, lanes (j=lane>>4, c=lane&15)
        int j = lane >> 4, c = lane & 15;
        float acc = 0.f;
        for (int t = start + j; t < end; t += 4) {
            int s = csr_src[t];
            float alpha = __expf(leaky(as_[s] + adn) - m) * inv;
            acc = fmaf(alpha, h[s * 16 + c], acc);
        }
        acc += __shfl_xor(acc, 16);
        acc += __shfl_xor(acc, 32);
        if (lane < 16) {
            float o = acc + bias[c];
            if (RELU) o = fmaxf(o, 0.f);
            out[wave * 16 + c] = o;
        }
    }
}

// ---------------- launch ----------------

extern "C" void kernel_launch(void* const* d_in, const int* in_sizes, int n_in,
                              void* d_out, int out_size, void* d_ws, size_t ws_size,
                              hipStream_t stream) {
    const float* x   = (const float*)d_in[0];
    const int*   ei  = (const int*)  d_in[1];
    const float* W1  = (const float*)d_in[3];
    const float* as1 = (const float*)d_in[4];
    const float* ad1 = (const float*)d_in[5];
    const float* b1  = (const float*)d_in[6];
    const float* W2  = (const float*)d_in[7];
    const float* as2 = (const float*)d_in[8];
    const float* ad2 = (const float*)d_in[9];
    const float* b2  = (const float*)d_in[10];
    const float* W3  = (const float*)d_in[11];
    const float* as3 = (const float*)d_in[12];
    const float* ad3 = (const float*)d_in[13];
    const float* b3  = (const float*)d_in[14];

    const int* srcp = ei;
    const int* dstp = ei + N_EDGES;

    char* ws = (char*)d_ws;
    size_t off = 0;
    auto alloc = [&](size_t bytes) -> void* {
        void* p = ws + off;
        off = (off + bytes + 255) & ~(size_t)255;
        return p;
    };
    int*   deg     = (int*)  alloc((N_NODES + 1) * sizeof(int));
    int*   rowptr  = (int*)  alloc((N_NODES + 1) * sizeof(int));
    int*   cursor  = (int*)  alloc(N_NODES * sizeof(int));
    int*   csr_src = (int*)  alloc(N_EDGES * sizeof(int));
    float* asb     = (float*)alloc(N_NODES * sizeof(float));
    float* adb     = (float*)alloc(N_NODES * sizeof(float));
    float* bufA    = (float*)alloc((size_t)N_NODES * 64 * sizeof(float));
    float* bufB    = (float*)alloc((size_t)N_NODES * 64 * sizeof(float));

    hipMemsetAsync(deg, 0, N_NODES * sizeof(int), stream);
    hipMemsetAsync(cursor, 0, N_NODES * sizeof(int), stream);

    const int EB = (N_EDGES + 255) / 256;
    hist_kernel<<<EB, 256, 0, stream>>>(dstp, deg, N_EDGES);
    scan_kernel<<<1, 1024, 0, stream>>>(deg, rowptr, N_NODES);
    scatter_kernel<<<EB, 256, 0, stream>>>(srcp, dstp, rowptr, cursor, csr_src, N_EDGES);

    const int NB4  = (N_NODES + 3) / 4;     // 4 rows/waves per 256-thread block
    const int NB16 = (N_NODES + 15) / 16;   // 16 rows per block (C=16 gemm)

    // layer 1: 128 -> 64, relu
    gemm_alpha<128, 64><<<NB4, 256, 0, stream>>>(x, W1, as1, ad1, bufB, asb, adb, N_NODES);
    agg_kernel<64, true><<<NB4, 256, 0, stream>>>(bufB, asb, adb, rowptr, csr_src, b1, bufA, N_NODES);

    // layer 2: 64 -> 64, relu
    gemm_alpha<64, 64><<<NB4, 256, 0, stream>>>(bufA, W2, as2, ad2, bufB, asb, adb, N_NODES);
    agg_kernel<64, true><<<NB4, 256, 0, stream>>>(bufB, asb, adb, rowptr, csr_src, b2, bufA, N_NODES);

    // layer 3: 64 -> 16, no relu
    gemm_alpha<64, 16><<<NB16, 256, 0, stream>>>(bufA, W3, as3, ad3, bufB, asb, adb, N_NODES);
    agg_kernel<16, false><<<NB4, 256, 0, stream>>>(bufB, asb, adb, rowptr, csr_src, b3, (float*)d_out, N_NODES);
}

// Round 2
// 471.548 us; speedup vs baseline: 1.5536x; 1.5536x over previous
//
#include <hip/hip_runtime.h>
#include <math.h>

#define N_NODES 50000
#define N_EDGES 1600000

// ---------------- CSR build ----------------

__global__ void hist_kernel(const int* __restrict__ dst, int* __restrict__ deg, int e) {
    int i = blockIdx.x * blockDim.x + threadIdx.x;
    if (i < e) atomicAdd(&deg[dst[i]], 1);
}

// chunked single-block scan: each thread serially sums a contiguous chunk,
// one 1024-wide Hillis-Steele over chunk sums, then serial writeback.
__global__ void scan_kernel(const int* __restrict__ deg, int* __restrict__ rowptr, int n) {
    __shared__ int ssum[1024];
    int chunk = (n + 1023) / 1024;
    int lo = threadIdx.x * chunk;
    int hi = lo + chunk; if (hi > n) hi = n;
    int s = 0;
    for (int i = lo; i < hi; ++i) s += deg[i];
    ssum[threadIdx.x] = s;
    __syncthreads();
    for (int off = 1; off < 1024; off <<= 1) {
        int t = (threadIdx.x >= off) ? ssum[threadIdx.x - off] : 0;
        __syncthreads();
        ssum[threadIdx.x] += t;
        __syncthreads();
    }
    int run = ssum[threadIdx.x] - s;   // exclusive prefix of this chunk
    for (int i = lo; i < hi; ++i) { rowptr[i] = run; run += deg[i]; }
    if (threadIdx.x == 1023) rowptr[n] = run;
}

__global__ void scatter_kernel(const int* __restrict__ src, const int* __restrict__ dst,
                               const int* __restrict__ rowptr, int* __restrict__ cursor,
                               int* __restrict__ csr_src, int e) {
    int i = blockIdx.x * blockDim.x + threadIdx.x;
    if (i < e) {
        int d = dst[i];
        int p = atomicAdd(&cursor[d], 1);
        csr_src[rowptr[d] + p] = src[i];
    }
}

// ---------------- h = in @ W ; as = h.a_src ; ad = h.a_dst ----------------

template<int K, int C>
__global__ __launch_bounds__(256) void gemm_alpha(
        const float* __restrict__ in, const float* __restrict__ W,
        const float* __restrict__ a_src, const float* __restrict__ a_dst,
        float* __restrict__ h, float* __restrict__ as_, float* __restrict__ ad_, int n)
{
    constexpr int ROWS = 256 / C;
    __shared__ float sx[ROWS * K];
    int row0 = blockIdx.x * ROWS;
    // contiguous float4 staging (rows are contiguous in memory)
    {
        const float4* srcp = (const float4*)(in + (size_t)row0 * K);
        float4* dstp = (float4*)sx;
        int n4 = ROWS * K / 4;
        int lim4 = (n - row0) * K / 4;           // N divisible by ROWS here, but keep guard
        for (int i = threadIdx.x; i < n4; i += 256)
            dstp[i] = (i < lim4) ? srcp[i] : float4{0, 0, 0, 0};
    }
    __syncthreads();
    int g = threadIdx.x / C;
    int c = threadIdx.x % C;
    int ni = row0 + g;
    const float* xr = &sx[g * K];
    float a0 = 0.f, a1 = 0.f, a2 = 0.f, a3 = 0.f;
#pragma unroll 4
    for (int k = 0; k < K; k += 4) {
        a0 = fmaf(xr[k + 0], W[(k + 0) * C + c], a0);
        a1 = fmaf(xr[k + 1], W[(k + 1) * C + c], a1);
        a2 = fmaf(xr[k + 2], W[(k + 2) * C + c], a2);
        a3 = fmaf(xr[k + 3], W[(k + 3) * C + c], a3);
    }
    float acc = (a0 + a1) + (a2 + a3);
    float vs = acc * a_src[c];
    float vd = acc * a_dst[c];
#pragma unroll
    for (int msk = 1; msk < C; msk <<= 1) {
        vs += __shfl_xor(vs, msk);
        vd += __shfl_xor(vd, msk);
    }
    if (ni < n) {
        h[(size_t)ni * C + c] = acc;
        if (c == 0) { as_[ni] = vs; ad_[ni] = vd; }
    }
}

// ---------------- fused single-pass softmax + aggregation ----------------
// alpha_e = exp(leaky(as[src]+ad[dst])) ; out = (sum alpha*h[src]) / (sum alpha + 1e-16)
// (no max subtraction: e is O(+-7), exp cannot overflow fp32)

__device__ __forceinline__ float leaky(float e) {
    return (e >= 0.f) ? e : 0.2f * e;
}

// C=64: one wave per node; 4 edge-groups x 16 lanes x float4
template<bool RELU>
__global__ __launch_bounds__(256) void agg64(
        const float* __restrict__ h, const float* __restrict__ as_, const float* __restrict__ ad_,
        const int* __restrict__ rowptr, const int* __restrict__ csr_src,
        const float* __restrict__ bias, float* __restrict__ out, int n)
{
    int node = (blockIdx.x * blockDim.x + threadIdx.x) >> 6;
    if (node >= n) return;
    int lane = threadIdx.x & 63;
    int g  = lane >> 4;       // edge group 0..3
    int c4 = lane & 15;       // float4 slot within 64-ch row
    int start = rowptr[node], end = rowptr[node + 1];
    float adn = ad_[node];

    float4 accA = {0,0,0,0}, accB = {0,0,0,0};
    float dA = 0.f, dB = 0.f;

    int t = start + g;
    for (; t + 4 < end; t += 8) {                 // edges t and t+4 both valid
        int sA = csr_src[t];
        int sB = csr_src[t + 4];
        float wA = __expf(leaky(as_[sA] + adn));
        float wB = __expf(leaky(as_[sB] + adn));
        float4 hA = *(const float4*)&h[(size_t)sA * 64 + c4 * 4];
        float4 hB = *(const float4*)&h[(size_t)sB * 64 + c4 * 4];
        accA.x = fmaf(wA, hA.x, accA.x); accA.y = fmaf(wA, hA.y, accA.y);
        accA.z = fmaf(wA, hA.z, accA.z); accA.w = fmaf(wA, hA.w, accA.w);
        accB.x = fmaf(wB, hB.x, accB.x); accB.y = fmaf(wB, hB.y, accB.y);
        accB.z = fmaf(wB, hB.z, accB.z); accB.w = fmaf(wB, hB.w, accB.w);
        dA += wA; dB += wB;
    }
    if (t < end) {
        int sA = csr_src[t];
        float wA = __expf(leaky(as_[sA] + adn));
        float4 hA = *(const float4*)&h[(size_t)sA * 64 + c4 * 4];
        accA.x = fmaf(wA, hA.x, accA.x); accA.y = fmaf(wA, hA.y, accA.y);
        accA.z = fmaf(wA, hA.z, accA.z); accA.w = fmaf(wA, hA.w, accA.w);
        dA += wA;
    }
    float4 a; a.x = accA.x + accB.x; a.y = accA.y + accB.y;
    a.z = accA.z + accB.z; a.w = accA.w + accB.w;
    float d = dA + dB;
#pragma unroll
    for (int off = 16; off <= 32; off <<= 1) {
        a.x += __shfl_xor(a.x, off); a.y += __shfl_xor(a.y, off);
        a.z += __shfl_xor(a.z, off); a.w += __shfl_xor(a.w, off);
        d += __shfl_xor(d, off);
    }
    if (g == 0) {
        float inv = 1.f / (d + 1e-16f);
        float4 bv = *(const float4*)&bias[c4 * 4];
        float4 o;
        o.x = fmaf(a.x, inv, bv.x); o.y = fmaf(a.y, inv, bv.y);
        o.z = fmaf(a.z, inv, bv.z); o.w = fmaf(a.w, inv, bv.w);
        if (RELU) {
            o.x = fmaxf(o.x, 0.f); o.y = fmaxf(o.y, 0.f);
            o.z = fmaxf(o.z, 0.f); o.w = fmaxf(o.w, 0.f);
        }
        *(float4*)&out[(size_t)node * 64 + c4 * 4] = o;
    }
}

// C=16: one wave per node; 16 edge-groups x 4 lanes x float4
template<bool RELU>
__global__ __launch_bounds__(256) void agg16(
        const float* __restrict__ h, const float* __restrict__ as_, const float* __restrict__ ad_,
        const int* __restrict__ rowptr, const int* __restrict__ csr_src,
        const float* __restrict__ bias, float* __restrict__ out, int n)
{
    int node = (blockIdx.x * blockDim.x + threadIdx.x) >> 6;
    if (node >= n) return;
    int lane = threadIdx.x & 63;
    int g  = lane >> 2;       // edge group 0..15
    int c4 = lane & 3;        // float4 slot within 16-ch row
    int start = rowptr[node], end = rowptr[node + 1];
    float adn = ad_[node];

    float4 acc = {0,0,0,0};
    float d = 0.f;
    for (int t = start + g; t < end; t += 16) {
        int s = csr_src[t];
        float w = __expf(leaky(as_[s] + adn));
        float4 hv = *(const float4*)&h[(size_t)s * 16 + c4 * 4];
        acc.x = fmaf(w, hv.x, acc.x); acc.y = fmaf(w, hv.y, acc.y);
        acc.z = fmaf(w, hv.z, acc.z); acc.w = fmaf(w, hv.w, acc.w);
        d += w;
    }
#pragma unroll
    for (int off = 4; off <= 32; off <<= 1) {
        acc.x += __shfl_xor(acc.x, off); acc.y += __shfl_xor(acc.y, off);
        acc.z += __shfl_xor(acc.z, off); acc.w += __shfl_xor(acc.w, off);
        d += __shfl_xor(d, off);
    }
    if (g == 0) {
        float inv = 1.f / (d + 1e-16f);
        float4 bv = *(const float4*)&bias[c4 * 4];
        float4 o;
        o.x = fmaf(acc.x, inv, bv.x); o.y = fmaf(acc.y, inv, bv.y);
        o.z = fmaf(acc.z, inv, bv.z); o.w = fmaf(acc.w, inv, bv.w);
        if (RELU) {
            o.x = fmaxf(o.x, 0.f); o.y = fmaxf(o.y, 0.f);
            o.z = fmaxf(o.z, 0.f); o.w = fmaxf(o.w, 0.f);
        }
        *(float4*)&out[(size_t)node * 16 + c4 * 4] = o;
    }
}

// ---------------- launch ----------------

extern "C" void kernel_launch(void* const* d_in, const int* in_sizes, int n_in,
                              void* d_out, int out_size, void* d_ws, size_t ws_size,
                              hipStream_t stream) {
    const float* x   = (const float*)d_in[0];
    const int*   ei  = (const int*)  d_in[1];
    const float* W1  = (const float*)d_in[3];
    const float* as1 = (const float*)d_in[4];
    const float* ad1 = (const float*)d_in[5];
    const float* b1  = (const float*)d_in[6];
    const float* W2  = (const float*)d_in[7];
    const float* as2 = (const float*)d_in[8];
    const float* ad2 = (const float*)d_in[9];
    const float* b2  = (const float*)d_in[10];
    const float* W3  = (const float*)d_in[11];
    const float* as3 = (const float*)d_in[12];
    const float* ad3 = (const float*)d_in[13];
    const float* b3  = (const float*)d_in[14];

    const int* srcp = ei;
    const int* dstp = ei + N_EDGES;

    char* ws = (char*)d_ws;
    size_t off = 0;
    auto alloc = [&](size_t bytes) -> void* {
        void* p = ws + off;
        off = (off + bytes + 255) & ~(size_t)255;
        return p;
    };
    int*   deg     = (int*)  alloc((N_NODES + 1) * sizeof(int));
    int*   rowptr  = (int*)  alloc((N_NODES + 1) * sizeof(int));
    int*   cursor  = (int*)  alloc(N_NODES * sizeof(int));
    int*   csr_src = (int*)  alloc(N_EDGES * sizeof(int));
    float* asb     = (float*)alloc(N_NODES * sizeof(float));
    float* adb     = (float*)alloc(N_NODES * sizeof(float));
    float* bufA    = (float*)alloc((size_t)N_NODES * 64 * sizeof(float));
    float* bufB    = (float*)alloc((size_t)N_NODES * 64 * sizeof(float));

    hipMemsetAsync(deg, 0, N_NODES * sizeof(int), stream);
    hipMemsetAsync(cursor, 0, N_NODES * sizeof(int), stream);

    const int EB = (N_EDGES + 255) / 256;
    hist_kernel<<<EB, 256, 0, stream>>>(dstp, deg, N_EDGES);
    scan_kernel<<<1, 1024, 0, stream>>>(deg, rowptr, N_NODES);
    scatter_kernel<<<EB, 256, 0, stream>>>(srcp, dstp, rowptr, cursor, csr_src, N_EDGES);

    const int NB4  = (N_NODES + 3) / 4;     // wave per node, 4 nodes/block
    const int NB16 = (N_NODES + 15) / 16;   // C=16 gemm: 16 rows/block

    // layer 1: 128 -> 64, relu
    gemm_alpha<128, 64><<<NB4, 256, 0, stream>>>(x, W1, as1, ad1, bufB, asb, adb, N_NODES);
    agg64<true><<<NB4, 256, 0, stream>>>(bufB, asb, adb, rowptr, csr_src, b1, bufA, N_NODES);

    // layer 2: 64 -> 64, relu
    gemm_alpha<64, 64><<<NB4, 256, 0, stream>>>(bufA, W2, as2, ad2, bufB, asb, adb, N_NODES);
    agg64<true><<<NB4, 256, 0, stream>>>(bufB, asb, adb, rowptr, csr_src, b2, bufA, N_NODES);

    // layer 3: 64 -> 16, no relu
    gemm_alpha<64, 16><<<NB16, 256, 0, stream>>>(bufA, W3, as3, ad3, bufB, asb, adb, N_NODES);
    agg16<false><<<NB4, 256, 0, stream>>>(bufB, asb, adb, rowptr, csr_src, b3, (float*)d_out, N_NODES);
}

// Round 3
// 330.933 us; speedup vs baseline: 2.2137x; 1.4249x over previous
//
#include <hip/hip_runtime.h>
#include <math.h>

#define N_NODES 50000
#define N_EDGES 1600000
#define BSH 6                                  // 64 nodes per bucket
#define NBUCK ((N_NODES + 63) >> BSH)          // 782

// ================= bucket-level CSR build =================

// per-block LDS histogram of dst-buckets, flushed with one atomic per nonzero bin
__global__ __launch_bounds__(256) void bucket_hist(const int* __restrict__ dst,
                                                   int* __restrict__ bcnt, int e) {
    __shared__ int h[NBUCK];
    for (int i = threadIdx.x; i < NBUCK; i += 256) h[i] = 0;
    __syncthreads();
    int base = blockIdx.x * 1024;
#pragma unroll
    for (int j = 0; j < 4; ++j) {
        int i = base + j * 256 + threadIdx.x;
        if (i < e) atomicAdd(&h[dst[i] >> BSH], 1);
    }
    __syncthreads();
    for (int i = threadIdx.x; i < NBUCK; i += 256)
        if (h[i]) atomicAdd(&bcnt[i], h[i]);
}

// single-block exclusive scan over NBUCK (<=1024) bucket counts
__global__ __launch_bounds__(1024) void scan_buckets(const int* __restrict__ bcnt,
                                                     int* __restrict__ bbase,
                                                     int* __restrict__ bcur,
                                                     int* __restrict__ rowptr) {
    __shared__ int s[1024];
    int i = threadIdx.x;
    int v = (i < NBUCK) ? bcnt[i] : 0;
    s[i] = v;
    __syncthreads();
    for (int off = 1; off < 1024; off <<= 1) {
        int t = (i >= off) ? s[i - off] : 0;
        __syncthreads();
        s[i] += t;
        __syncthreads();
    }
    if (i < NBUCK) { bbase[i] = s[i] - v; bcur[i] = s[i] - v; }
    if (i == NBUCK - 1) { bbase[NBUCK] = s[i]; rowptr[N_NODES] = s[i]; }
}

// scatter edges into bucket regions as packed (dloc<<16 | src); block-contiguous runs
__global__ __launch_bounds__(256) void bucket_scatter(const int* __restrict__ src,
                                                      const int* __restrict__ dst,
                                                      int* __restrict__ bcur,
                                                      unsigned* __restrict__ packed, int e) {
    __shared__ int lcnt[NBUCK];
    __shared__ int lbase[NBUCK];
    for (int i = threadIdx.x; i < NBUCK; i += 256) lcnt[i] = 0;
    __syncthreads();
    int base = blockIdx.x * 1024;
    int bk[4], lrank[4];
    unsigned pk[4];
    bool val[4];
#pragma unroll
    for (int j = 0; j < 4; ++j) {
        int i = base + j * 256 + threadIdx.x;
        val[j] = (i < e);
        if (val[j]) {
            int d = dst[i];
            bk[j] = d >> BSH;
            pk[j] = (unsigned)src[i] | ((unsigned)(d & 63) << 16);
            lrank[j] = atomicAdd(&lcnt[bk[j]], 1);
        }
    }
    __syncthreads();
    for (int i = threadIdx.x; i < NBUCK; i += 256)
        if (lcnt[i]) lbase[i] = atomicAdd(&bcur[i], lcnt[i]);
    __syncthreads();
#pragma unroll
    for (int j = 0; j < 4; ++j)
        if (val[j]) packed[lbase[bk[j]] + lrank[j]] = pk[j];
}

// block per bucket: counting-sort by local node, emit rowptr + csr_src
__global__ __launch_bounds__(256) void csr_finalize(const unsigned* __restrict__ packed,
                                                    const int* __restrict__ bbase,
                                                    int* __restrict__ rowptr,
                                                    int* __restrict__ csr_src) {
    int b = blockIdx.x;
    int s0 = bbase[b], s1 = bbase[b + 1];
    int cnt = s1 - s0;
    __shared__ int ncnt[64];
    __shared__ int ncur[64];
    if (threadIdx.x < 64) ncnt[threadIdx.x] = 0;
    __syncthreads();
    for (int i = threadIdx.x; i < cnt; i += 256)
        atomicAdd(&ncnt[packed[s0 + i] >> 16], 1);
    __syncthreads();
    if (threadIdx.x < 64) {                      // wave 0: exclusive scan of 64 counts
        int v = ncnt[threadIdx.x];
        int inc = v;
#pragma unroll
        for (int off = 1; off < 64; off <<= 1) {
            int t = __shfl_up(inc, off);
            if ((int)threadIdx.x >= off) inc += t;
        }
        int excl = inc - v;
        int node = (b << BSH) + threadIdx.x;
        if (node < N_NODES) rowptr[node] = s0 + excl;
        ncur[threadIdx.x] = s0 + excl;
    }
    __syncthreads();
    for (int i = threadIdx.x; i < cnt; i += 256) {
        unsigned p = packed[s0 + i];
        int pos = atomicAdd(&ncur[p >> 16], 1);
        csr_src[pos] = (int)(p & 0xFFFFu);       // block-private 8KB window: L2-coalesced
    }
}

// ================= h = in @ W ; as = h.a_src ; ad = h.a_dst =================

template<int K, int C>
__global__ __launch_bounds__(256) void gemm_alpha(
        const float* __restrict__ in, const float* __restrict__ W,
        const float* __restrict__ a_src, const float* __restrict__ a_dst,
        float* __restrict__ h, float* __restrict__ as_, float* __restrict__ ad_, int n)
{
    constexpr int ROWS = 256 / C;
    __shared__ float sx[ROWS * K];
    int row0 = blockIdx.x * ROWS;
    {
        const float4* srcp = (const float4*)(in + (size_t)row0 * K);
        float4* dstp = (float4*)sx;
        int n4 = ROWS * K / 4;
        int lim4 = (n - row0) * K / 4;
        for (int i = threadIdx.x; i < n4; i += 256)
            dstp[i] = (i < lim4) ? srcp[i] : float4{0, 0, 0, 0};
    }
    __syncthreads();
    int g = threadIdx.x / C;
    int c = threadIdx.x % C;
    int ni = row0 + g;
    const float* xr = &sx[g * K];
    float a0 = 0.f, a1 = 0.f, a2 = 0.f, a3 = 0.f;
#pragma unroll 4
    for (int k = 0; k < K; k += 4) {
        a0 = fmaf(xr[k + 0], W[(k + 0) * C + c], a0);
        a1 = fmaf(xr[k + 1], W[(k + 1) * C + c], a1);
        a2 = fmaf(xr[k + 2], W[(k + 2) * C + c], a2);
        a3 = fmaf(xr[k + 3], W[(k + 3) * C + c], a3);
    }
    float acc = (a0 + a1) + (a2 + a3);
    float vs = acc * a_src[c];
    float vd = acc * a_dst[c];
#pragma unroll
    for (int msk = 1; msk < C; msk <<= 1) {
        vs += __shfl_xor(vs, msk);
        vd += __shfl_xor(vd, msk);
    }
    if (ni < n) {
        h[(size_t)ni * C + c] = acc;
        if (c == 0) { as_[ni] = vs; ad_[ni] = vd; }
    }
}

// ================= fused single-pass softmax + aggregation =================
// alpha_e = exp(leaky(as[src]+ad[dst])); out = (sum alpha*h[src])/(sum alpha + 1e-16)
// no max subtraction: e is O(+-7), exp cannot overflow fp32

__device__ __forceinline__ float leaky(float e) {
    return (e >= 0.f) ? e : 0.2f * e;
}

template<bool RELU>
__global__ __launch_bounds__(256) void agg64(
        const float* __restrict__ h, const float* __restrict__ as_, const float* __restrict__ ad_,
        const int* __restrict__ rowptr, const int* __restrict__ csr_src,
        const float* __restrict__ bias, float* __restrict__ out, int n)
{
    int node = (blockIdx.x * blockDim.x + threadIdx.x) >> 6;
    if (node >= n) return;
    int lane = threadIdx.x & 63;
    int g  = lane >> 4;
    int c4 = lane & 15;
    int start = rowptr[node], end = rowptr[node + 1];
    float adn = ad_[node];

    float4 accA = {0,0,0,0}, accB = {0,0,0,0};
    float dA = 0.f, dB = 0.f;

    int t = start + g;
    for (; t + 4 < end; t += 8) {
        int sA = csr_src[t];
        int sB = csr_src[t + 4];
        float wA = __expf(leaky(as_[sA] + adn));
        float wB = __expf(leaky(as_[sB] + adn));
        float4 hA = *(const float4*)&h[(size_t)sA * 64 + c4 * 4];
        float4 hB = *(const float4*)&h[(size_t)sB * 64 + c4 * 4];
        accA.x = fmaf(wA, hA.x, accA.x); accA.y = fmaf(wA, hA.y, accA.y);
        accA.z = fmaf(wA, hA.z, accA.z); accA.w = fmaf(wA, hA.w, accA.w);
        accB.x = fmaf(wB, hB.x, accB.x); accB.y = fmaf(wB, hB.y, accB.y);
        accB.z = fmaf(wB, hB.z, accB.z); accB.w = fmaf(wB, hB.w, accB.w);
        dA += wA; dB += wB;
    }
    if (t < end) {
        int sA = csr_src[t];
        float wA = __expf(leaky(as_[sA] + adn));
        float4 hA = *(const float4*)&h[(size_t)sA * 64 + c4 * 4];
        accA.x = fmaf(wA, hA.x, accA.x); accA.y = fmaf(wA, hA.y, accA.y);
        accA.z = fmaf(wA, hA.z, accA.z); accA.w = fmaf(wA, hA.w, accA.w);
        dA += wA;
    }
    float4 a; a.x = accA.x + accB.x; a.y = accA.y + accB.y;
    a.z = accA.z + accB.z; a.w = accA.w + accB.w;
    float d = dA + dB;
#pragma unroll
    for (int off = 16; off <= 32; off <<= 1) {
        a.x += __shfl_xor(a.x, off); a.y += __shfl_xor(a.y, off);
        a.z += __shfl_xor(a.z, off); a.w += __shfl_xor(a.w, off);
        d += __shfl_xor(d, off);
    }
    if (g == 0) {
        float inv = 1.f / (d + 1e-16f);
        float4 bv = *(const float4*)&bias[c4 * 4];
        float4 o;
        o.x = fmaf(a.x, inv, bv.x); o.y = fmaf(a.y, inv, bv.y);
        o.z = fmaf(a.z, inv, bv.z); o.w = fmaf(a.w, inv, bv.w);
        if (RELU) {
            o.x = fmaxf(o.x, 0.f); o.y = fmaxf(o.y, 0.f);
            o.z = fmaxf(o.z, 0.f); o.w = fmaxf(o.w, 0.f);
        }
        *(float4*)&out[(size_t)node * 64 + c4 * 4] = o;
    }
}

template<bool RELU>
__global__ __launch_bounds__(256) void agg16(
        const float* __restrict__ h, const float* __restrict__ as_, const float* __restrict__ ad_,
        const int* __restrict__ rowptr, const int* __restrict__ csr_src,
        const float* __restrict__ bias, float* __restrict__ out, int n)
{
    int node = (blockIdx.x * blockDim.x + threadIdx.x) >> 6;
    if (node >= n) return;
    int lane = threadIdx.x & 63;
    int g  = lane >> 2;
    int c4 = lane & 3;
    int start = rowptr[node], end = rowptr[node + 1];
    float adn = ad_[node];

    float4 acc = {0,0,0,0};
    float d = 0.f;
    for (int t = start + g; t < end; t += 16) {
        int s = csr_src[t];
        float w = __expf(leaky(as_[s] + adn));
        float4 hv = *(const float4*)&h[(size_t)s * 16 + c4 * 4];
        acc.x = fmaf(w, hv.x, acc.x); acc.y = fmaf(w, hv.y, acc.y);
        acc.z = fmaf(w, hv.z, acc.z); acc.w = fmaf(w, hv.w, acc.w);
        d += w;
    }
#pragma unroll
    for (int off = 4; off <= 32; off <<= 1) {
        acc.x += __shfl_xor(acc.x, off); acc.y += __shfl_xor(acc.y, off);
        acc.z += __shfl_xor(acc.z, off); acc.w += __shfl_xor(acc.w, off);
        d += __shfl_xor(d, off);
    }
    if (g == 0) {
        float inv = 1.f / (d + 1e-16f);
        float4 bv = *(const float4*)&bias[c4 * 4];
        float4 o;
        o.x = fmaf(acc.x, inv, bv.x); o.y = fmaf(acc.y, inv, bv.y);
        o.z = fmaf(acc.z, inv, bv.z); o.w = fmaf(acc.w, inv, bv.w);
        if (RELU) {
            o.x = fmaxf(o.x, 0.f); o.y = fmaxf(o.y, 0.f);
            o.z = fmaxf(o.z, 0.f); o.w = fmaxf(o.w, 0.f);
        }
        *(float4*)&out[(size_t)node * 16 + c4 * 4] = o;
    }
}

// ================= launch =================

extern "C" void kernel_launch(void* const* d_in, const int* in_sizes, int n_in,
                              void* d_out, int out_size, void* d_ws, size_t ws_size,
                              hipStream_t stream) {
    const float* x   = (const float*)d_in[0];
    const int*   ei  = (const int*)  d_in[1];
    const float* W1  = (const float*)d_in[3];
    const float* as1 = (const float*)d_in[4];
    const float* ad1 = (const float*)d_in[5];
    const float* b1  = (const float*)d_in[6];
    const float* W2  = (const float*)d_in[7];
    const float* as2 = (const float*)d_in[8];
    const float* ad2 = (const float*)d_in[9];
    const float* b2  = (const float*)d_in[10];
    const float* W3  = (const float*)d_in[11];
    const float* as3 = (const float*)d_in[12];
    const float* ad3 = (const float*)d_in[13];
    const float* b3  = (const float*)d_in[14];

    const int* srcp = ei;
    const int* dstp = ei + N_EDGES;

    char* ws = (char*)d_ws;
    size_t off = 0;
    auto alloc = [&](size_t bytes) -> void* {
        void* p = ws + off;
        off = (off + bytes + 255) & ~(size_t)255;
        return p;
    };
    int*   bcnt    = (int*)  alloc(NBUCK * sizeof(int));
    int*   bbase   = (int*)  alloc((NBUCK + 1) * sizeof(int));
    int*   bcur    = (int*)  alloc(NBUCK * sizeof(int));
    int*   rowptr  = (int*)  alloc((N_NODES + 1) * sizeof(int));
    int*   csr_src = (int*)  alloc(N_EDGES * sizeof(int));
    float* asb     = (float*)alloc(N_NODES * sizeof(float));
    float* adb     = (float*)alloc(N_NODES * sizeof(float));
    float* bufA    = (float*)alloc((size_t)N_NODES * 64 * sizeof(float));
    float* bufB    = (float*)alloc((size_t)N_NODES * 64 * sizeof(float));
    // packed edge buffer aliases bufA: dead before agg1 writes bufA
    unsigned* packed = (unsigned*)bufA;

    hipMemsetAsync(bcnt, 0, NBUCK * sizeof(int), stream);

    const int EB1024 = (N_EDGES + 1023) / 1024;
    bucket_hist   <<<EB1024, 256,  0, stream>>>(dstp, bcnt, N_EDGES);
    scan_buckets  <<<1,      1024, 0, stream>>>(bcnt, bbase, bcur, rowptr);
    bucket_scatter<<<EB1024, 256,  0, stream>>>(srcp, dstp, bcur, packed, N_EDGES);
    csr_finalize  <<<NBUCK,  256,  0, stream>>>(packed, bbase, rowptr, csr_src);

    const int NB4  = (N_NODES + 3) / 4;
    const int NB16 = (N_NODES + 15) / 16;

    // layer 1: 128 -> 64, relu
    gemm_alpha<128, 64><<<NB4, 256, 0, stream>>>(x, W1, as1, ad1, bufB, asb, adb, N_NODES);
    agg64<true><<<NB4, 256, 0, stream>>>(bufB, asb, adb, rowptr, csr_src, b1, bufA, N_NODES);

    // layer 2: 64 -> 64, relu
    gemm_alpha<64, 64><<<NB4, 256, 0, stream>>>(bufA, W2, as2, ad2, bufB, asb, adb, N_NODES);
    agg64<true><<<NB4, 256, 0, stream>>>(bufB, asb, adb, rowptr, csr_src, b2, bufA, N_NODES);

    // layer 3: 64 -> 16, no relu
    gemm_alpha<64, 16><<<NB16, 256, 0, stream>>>(bufA, W3, as3, ad3, bufB, asb, adb, N_NODES);
    agg16<false><<<NB4, 256, 0, stream>>>(bufB, asb, adb, rowptr, csr_src, b3, (float*)d_out, N_NODES);
}

// Round 4
// 302.323 us; speedup vs baseline: 2.4232x; 1.0946x over previous
//
#include <hip/hip_runtime.h>
#include <math.h>

#define N_NODES 50000
#define N_EDGES 1600000
#define BSH 8                                   // 256 nodes per bucket
#define NBUCK ((N_NODES + 255) >> BSH)          // 196
#define EPB 4096                                // edges per scatter/hist block
#define NBLK ((N_EDGES + EPB - 1) / EPB)        // 391

// ================= CSR build (atomic-free at global scope) =================

// per-block LDS histogram of dst-buckets -> transposed count table
__global__ __launch_bounds__(256) void bucket_hist(const int* __restrict__ dst,
                                                   int* __restrict__ bhist_t, int e) {
    __shared__ int h[NBUCK];
    for (int i = threadIdx.x; i < NBUCK; i += 256) h[i] = 0;
    __syncthreads();
    int base = blockIdx.x * EPB;
#pragma unroll
    for (int j = 0; j < EPB / 256; ++j) {
        int i = base + j * 256 + threadIdx.x;
        if (i < e) atomicAdd(&h[dst[i] >> BSH], 1);      // no-return LDS atomic
    }
    __syncthreads();
    for (int i = threadIdx.x; i < NBUCK; i += 256)
        bhist_t[i * NBLK + blockIdx.x] = h[i];
}

// single block: column-sum -> bucket totals -> exclusive scan -> rewrite
// bhist_t in place as per-(block,bucket) base offsets
__global__ __launch_bounds__(256) void scan_buckets(int* __restrict__ bhist_t,
                                                    int* __restrict__ bbase,
                                                    int* __restrict__ rowptr) {
    __shared__ int s[256];
    int b = threadIdx.x;
    int tot = 0;
    if (b < NBUCK) {
        const int* col = bhist_t + b * NBLK;
#pragma unroll 8
        for (int r = 0; r < NBLK; ++r) tot += col[r];    // contiguous per thread
    }
    s[b] = tot;
    __syncthreads();
    for (int off = 1; off < 256; off <<= 1) {
        int t = (b >= off) ? s[b - off] : 0;
        __syncthreads();
        s[b] += t;
        __syncthreads();
    }
    int excl = s[b] - tot;
    if (b < NBUCK) {
        bbase[b] = excl;
        int* col = bhist_t + b * NBLK;
        int run = excl;
#pragma unroll 8
        for (int r = 0; r < NBLK; ++r) { int c = col[r]; col[r] = run; run += c; }
    }
    if (b == NBUCK - 1) { bbase[NBUCK] = s[b]; rowptr[N_NODES] = s[b]; }
}

// scatter edges into bucket regions at precomputed bases; packed (dloc<<16 | src)
__global__ __launch_bounds__(256) void bucket_scatter(const int* __restrict__ src,
                                                      const int* __restrict__ dst,
                                                      const int* __restrict__ bhist_t,
                                                      unsigned* __restrict__ packed, int e) {
    __shared__ int lcur[NBUCK];
    int r = blockIdx.x;
    for (int i = threadIdx.x; i < NBUCK; i += 256)
        lcur[i] = bhist_t[i * NBLK + r];
    __syncthreads();
    int base = r * EPB;
#pragma unroll
    for (int j = 0; j < EPB / 256; ++j) {
        int i = base + j * 256 + threadIdx.x;
        if (i < e) {
            int d = dst[i];
            int pos = atomicAdd(&lcur[d >> BSH], 1);     // LDS atomic only
            packed[pos] = (unsigned)src[i] | ((unsigned)(d & ((1 << BSH) - 1)) << 16);
        }
    }
}

// block per bucket: counting-sort by local node, emit rowptr + csr_src
__global__ __launch_bounds__(512) void csr_finalize(const unsigned* __restrict__ packed,
                                                    const int* __restrict__ bbase,
                                                    int* __restrict__ rowptr,
                                                    int* __restrict__ csr_src) {
    int b = blockIdx.x;
    int s0 = bbase[b], s1 = bbase[b + 1];
    int cnt = s1 - s0;
    __shared__ int ncnt[256];
    __shared__ int ncur[256];
    __shared__ int wsum[4];
    if (threadIdx.x < 256) ncnt[threadIdx.x] = 0;
    __syncthreads();
    for (int i = threadIdx.x; i < cnt; i += 512)
        atomicAdd(&ncnt[packed[s0 + i] >> 16], 1);
    __syncthreads();
    int lane = threadIdx.x & 63, w = threadIdx.x >> 6;
    int v = 0, inc = 0;
    if (threadIdx.x < 256) {                             // 4 waves scan 256 counts
        v = ncnt[threadIdx.x]; inc = v;
#pragma unroll
        for (int off = 1; off < 64; off <<= 1) {
            int t = __shfl_up(inc, off);
            if (lane >= off) inc += t;
        }
        if (lane == 63) wsum[w] = inc;
    }
    __syncthreads();
    if (threadIdx.x < 256) {
        int woff = 0;
#pragma unroll
        for (int k = 0; k < 3; ++k) if (k < w) woff += wsum[k];
        int excl = woff + inc - v;
        int node = (b << BSH) + threadIdx.x;
        if (node < N_NODES) rowptr[node] = s0 + excl;
        ncur[threadIdx.x] = s0 + excl;
    }
    __syncthreads();
    for (int i = threadIdx.x; i < cnt; i += 512) {
        unsigned p = packed[s0 + i];
        int pos = atomicAdd(&ncur[p >> 16], 1);
        csr_src[pos] = (int)(p & 0xFFFFu);               // 32KB window: L2-local
    }
}

// ================= h = in @ W ; as = h.a_src ; ad = h.a_dst =================

template<int K, int C>
__global__ __launch_bounds__(256) void gemm_alpha(
        const float* __restrict__ in, const float* __restrict__ W,
        const float* __restrict__ a_src, const float* __restrict__ a_dst,
        float* __restrict__ h, float* __restrict__ as_, float* __restrict__ ad_, int n)
{
    constexpr int ROWS = 256 / C;
    __shared__ float sx[ROWS * K];
    int row0 = blockIdx.x * ROWS;
    {
        const float4* srcp = (const float4*)(in + (size_t)row0 * K);
        float4* dstp = (float4*)sx;
        int n4 = ROWS * K / 4;
        int lim4 = (n - row0) * K / 4;
        for (int i = threadIdx.x; i < n4; i += 256)
            dstp[i] = (i < lim4) ? srcp[i] : float4{0, 0, 0, 0};
    }
    __syncthreads();
    int g = threadIdx.x / C;
    int c = threadIdx.x % C;
    int ni = row0 + g;
    const float* xr = &sx[g * K];
    float a0 = 0.f, a1 = 0.f, a2 = 0.f, a3 = 0.f;
#pragma unroll 4
    for (int k = 0; k < K; k += 4) {
        a0 = fmaf(xr[k + 0], W[(k + 0) * C + c], a0);
        a1 = fmaf(xr[k + 1], W[(k + 1) * C + c], a1);
        a2 = fmaf(xr[k + 2], W[(k + 2) * C + c], a2);
        a3 = fmaf(xr[k + 3], W[(k + 3) * C + c], a3);
    }
    float acc = (a0 + a1) + (a2 + a3);
    float vs = acc * a_src[c];
    float vd = acc * a_dst[c];
#pragma unroll
    for (int msk = 1; msk < C; msk <<= 1) {
        vs += __shfl_xor(vs, msk);
        vd += __shfl_xor(vd, msk);
    }
    if (ni < n) {
        h[(size_t)ni * C + c] = acc;
        if (c == 0) { as_[ni] = vs; ad_[ni] = vd; }
    }
}

// ================= fused single-pass softmax + aggregation =================
// alpha_e = exp(leaky(as[src]+ad[dst])); out = (sum alpha*h[src])/(sum alpha + 1e-16)
// no max subtraction: e is O(+-7), exp cannot overflow fp32

__device__ __forceinline__ float leaky(float e) {
    return (e >= 0.f) ? e : 0.2f * e;
}

template<bool RELU>
__global__ __launch_bounds__(256) void agg64(
        const float* __restrict__ h, const float* __restrict__ as_, const float* __restrict__ ad_,
        const int* __restrict__ rowptr, const int* __restrict__ csr_src,
        const float* __restrict__ bias, float* __restrict__ out, int n)
{
    int node = (blockIdx.x * blockDim.x + threadIdx.x) >> 6;
    if (node >= n) return;
    int lane = threadIdx.x & 63;
    int g  = lane >> 4;
    int c4 = lane & 15;
    int start = rowptr[node], end = rowptr[node + 1];
    float adn = ad_[node];

    float4 accA = {0,0,0,0}, accB = {0,0,0,0};
    float dA = 0.f, dB = 0.f;

    int t = start + g;
    for (; t + 4 < end; t += 8) {
        int sA = csr_src[t];
        int sB = csr_src[t + 4];
        float wA = __expf(leaky(as_[sA] + adn));
        float wB = __expf(leaky(as_[sB] + adn));
        float4 hA = *(const float4*)&h[(size_t)sA * 64 + c4 * 4];
        float4 hB = *(const float4*)&h[(size_t)sB * 64 + c4 * 4];
        accA.x = fmaf(wA, hA.x, accA.x); accA.y = fmaf(wA, hA.y, accA.y);
        accA.z = fmaf(wA, hA.z, accA.z); accA.w = fmaf(wA, hA.w, accA.w);
        accB.x = fmaf(wB, hB.x, accB.x); accB.y = fmaf(wB, hB.y, accB.y);
        accB.z = fmaf(wB, hB.z, accB.z); accB.w = fmaf(wB, hB.w, accB.w);
        dA += wA; dB += wB;
    }
    if (t < end) {
        int sA = csr_src[t];
        float wA = __expf(leaky(as_[sA] + adn));
        float4 hA = *(const float4*)&h[(size_t)sA * 64 + c4 * 4];
        accA.x = fmaf(wA, hA.x, accA.x); accA.y = fmaf(wA, hA.y, accA.y);
        accA.z = fmaf(wA, hA.z, accA.z); accA.w = fmaf(wA, hA.w, accA.w);
        dA += wA;
    }
    float4 a; a.x = accA.x + accB.x; a.y = accA.y + accB.y;
    a.z = accA.z + accB.z; a.w = accA.w + accB.w;
    float d = dA + dB;
#pragma unroll
    for (int off = 16; off <= 32; off <<= 1) {
        a.x += __shfl_xor(a.x, off); a.y += __shfl_xor(a.y, off);
        a.z += __shfl_xor(a.z, off); a.w += __shfl_xor(a.w, off);
        d += __shfl_xor(d, off);
    }
    if (g == 0) {
        float inv = 1.f / (d + 1e-16f);
        float4 bv = *(const float4*)&bias[c4 * 4];
        float4 o;
        o.x = fmaf(a.x, inv, bv.x); o.y = fmaf(a.y, inv, bv.y);
        o.z = fmaf(a.z, inv, bv.z); o.w = fmaf(a.w, inv, bv.w);
        if (RELU) {
            o.x = fmaxf(o.x, 0.f); o.y = fmaxf(o.y, 0.f);
            o.z = fmaxf(o.z, 0.f); o.w = fmaxf(o.w, 0.f);
        }
        *(float4*)&out[(size_t)node * 64 + c4 * 4] = o;
    }
}

template<bool RELU>
__global__ __launch_bounds__(256) void agg16(
        const float* __restrict__ h, const float* __restrict__ as_, const float* __restrict__ ad_,
        const int* __restrict__ rowptr, const int* __restrict__ csr_src,
        const float* __restrict__ bias, float* __restrict__ out, int n)
{
    int node = (blockIdx.x * blockDim.x + threadIdx.x) >> 6;
    if (node >= n) return;
    int lane = threadIdx.x & 63;
    int g  = lane >> 2;
    int c4 = lane & 3;
    int start = rowptr[node], end = rowptr[node + 1];
    float adn = ad_[node];

    float4 acc = {0,0,0,0};
    float d = 0.f;
    for (int t = start + g; t < end; t += 16) {
        int s = csr_src[t];
        float w = __expf(leaky(as_[s] + adn));
        float4 hv = *(const float4*)&h[(size_t)s * 16 + c4 * 4];
        acc.x = fmaf(w, hv.x, acc.x); acc.y = fmaf(w, hv.y, acc.y);
        acc.z = fmaf(w, hv.z, acc.z); acc.w = fmaf(w, hv.w, acc.w);
        d += w;
    }
#pragma unroll
    for (int off = 4; off <= 32; off <<= 1) {
        acc.x += __shfl_xor(acc.x, off); acc.y += __shfl_xor(acc.y, off);
        acc.z += __shfl_xor(acc.z, off); acc.w += __shfl_xor(acc.w, off);
        d += __shfl_xor(d, off);
    }
    if (g == 0) {
        float inv = 1.f / (d + 1e-16f);
        float4 bv = *(const float4*)&bias[c4 * 4];
        float4 o;
        o.x = fmaf(acc.x, inv, bv.x); o.y = fmaf(acc.y, inv, bv.y);
        o.z = fmaf(acc.z, inv, bv.z); o.w = fmaf(acc.w, inv, bv.w);
        if (RELU) {
            o.x = fmaxf(o.x, 0.f); o.y = fmaxf(o.y, 0.f);
            o.z = fmaxf(o.z, 0.f); o.w = fmaxf(o.w, 0.f);
        }
        *(float4*)&out[(size_t)node * 16 + c4 * 4] = o;
    }
}

// ================= launch =================

extern "C" void kernel_launch(void* const* d_in, const int* in_sizes, int n_in,
                              void* d_out, int out_size, void* d_ws, size_t ws_size,
                              hipStream_t stream) {
    const float* x   = (const float*)d_in[0];
    const int*   ei  = (const int*)  d_in[1];
    const float* W1  = (const float*)d_in[3];
    const float* as1 = (const float*)d_in[4];
    const float* ad1 = (const float*)d_in[5];
    const float* b1  = (const float*)d_in[6];
    const float* W2  = (const float*)d_in[7];
    const float* as2 = (const float*)d_in[8];
    const float* ad2 = (const float*)d_in[9];
    const float* b2  = (const float*)d_in[10];
    const float* W3  = (const float*)d_in[11];
    const float* as3 = (const float*)d_in[12];
    const float* ad3 = (const float*)d_in[13];
    const float* b3  = (const float*)d_in[14];

    const int* srcp = ei;
    const int* dstp = ei + N_EDGES;

    char* ws = (char*)d_ws;
    size_t off = 0;
    auto alloc = [&](size_t bytes) -> void* {
        void* p = ws + off;
        off = (off + bytes + 255) & ~(size_t)255;
        return p;
    };
    int*   bhist_t = (int*)  alloc((size_t)NBUCK * NBLK * sizeof(int));
    int*   bbase   = (int*)  alloc((NBUCK + 1) * sizeof(int));
    int*   rowptr  = (int*)  alloc((N_NODES + 1) * sizeof(int));
    int*   csr_src = (int*)  alloc(N_EDGES * sizeof(int));
    float* asb     = (float*)alloc(N_NODES * sizeof(float));
    float* adb     = (float*)alloc(N_NODES * sizeof(float));
    float* bufA    = (float*)alloc((size_t)N_NODES * 64 * sizeof(float));
    float* bufB    = (float*)alloc((size_t)N_NODES * 64 * sizeof(float));
    // packed edge buffer aliases bufA: dead before agg1 writes bufA
    unsigned* packed = (unsigned*)bufA;

    bucket_hist   <<<NBLK,  256, 0, stream>>>(dstp, bhist_t, N_EDGES);
    scan_buckets  <<<1,     256, 0, stream>>>(bhist_t, bbase, rowptr);
    bucket_scatter<<<NBLK,  256, 0, stream>>>(srcp, dstp, bhist_t, packed, N_EDGES);
    csr_finalize  <<<NBUCK, 512, 0, stream>>>(packed, bbase, rowptr, csr_src);

    const int NB4  = (N_NODES + 3) / 4;
    const int NB16 = (N_NODES + 15) / 16;

    // layer 1: 128 -> 64, relu
    gemm_alpha<128, 64><<<NB4, 256, 0, stream>>>(x, W1, as1, ad1, bufB, asb, adb, N_NODES);
    agg64<true><<<NB4, 256, 0, stream>>>(bufB, asb, adb, rowptr, csr_src, b1, bufA, N_NODES);

    // layer 2: 64 -> 64, relu
    gemm_alpha<64, 64><<<NB4, 256, 0, stream>>>(bufA, W2, as2, ad2, bufB, asb, adb, N_NODES);
    agg64<true><<<NB4, 256, 0, stream>>>(bufB, asb, adb, rowptr, csr_src, b2, bufA, N_NODES);

    // layer 3: 64 -> 16, no relu
    gemm_alpha<64, 16><<<NB16, 256, 0, stream>>>(bufA, W3, as3, ad3, bufB, asb, adb, N_NODES);
    agg16<false><<<NB4, 256, 0, stream>>>(bufB, asb, adb, rowptr, csr_src, b3, (float*)d_out, N_NODES);
}

// Round 5
// 268.186 us; speedup vs baseline: 2.7317x; 1.1273x over previous
//
#include <hip/hip_runtime.h>
#include <math.h>

#define N_NODES 50000
#define N_EDGES 1600000
#define BSH 8                                   // 256 nodes per bucket
#define NBUCK ((N_NODES + 255) >> BSH)          // 196
#define EPB 4096                                // edges per scatter/hist block
#define NBLK ((N_EDGES + EPB - 1) / EPB)        // 391

// ================= CSR build (atomic-free at global scope) =================

__global__ __launch_bounds__(256) void bucket_hist(const int* __restrict__ dst,
                                                   int* __restrict__ bhist_t, int e) {
    __shared__ int h[NBUCK];
    for (int i = threadIdx.x; i < NBUCK; i += 256) h[i] = 0;
    __syncthreads();
    int base = blockIdx.x * EPB;
#pragma unroll
    for (int j = 0; j < EPB / 256; ++j) {
        int i = base + j * 256 + threadIdx.x;
        if (i < e) atomicAdd(&h[dst[i] >> BSH], 1);
    }
    __syncthreads();
    for (int i = threadIdx.x; i < NBUCK; i += 256)
        bhist_t[i * NBLK + blockIdx.x] = h[i];
}

__global__ __launch_bounds__(256) void scan_buckets(int* __restrict__ bhist_t,
                                                    int* __restrict__ bbase,
                                                    int* __restrict__ rowptr) {
    __shared__ int s[256];
    int b = threadIdx.x;
    int tot = 0;
    if (b < NBUCK) {
        const int* col = bhist_t + b * NBLK;
#pragma unroll 8
        for (int r = 0; r < NBLK; ++r) tot += col[r];
    }
    s[b] = tot;
    __syncthreads();
    for (int off = 1; off < 256; off <<= 1) {
        int t = (b >= off) ? s[b - off] : 0;
        __syncthreads();
        s[b] += t;
        __syncthreads();
    }
    int excl = s[b] - tot;
    if (b < NBUCK) {
        bbase[b] = excl;
        int* col = bhist_t + b * NBLK;
        int run = excl;
#pragma unroll 8
        for (int r = 0; r < NBLK; ++r) { int c = col[r]; col[r] = run; run += c; }
    }
    if (b == NBUCK - 1) { bbase[NBUCK] = s[b]; rowptr[N_NODES] = s[b]; }
}

__global__ __launch_bounds__(256) void bucket_scatter(const int* __restrict__ src,
                                                      const int* __restrict__ dst,
                                                      const int* __restrict__ bhist_t,
                                                      unsigned* __restrict__ packed, int e) {
    __shared__ int lcur[NBUCK];
    int r = blockIdx.x;
    for (int i = threadIdx.x; i < NBUCK; i += 256)
        lcur[i] = bhist_t[i * NBLK + r];
    __syncthreads();
    int base = r * EPB;
#pragma unroll
    for (int j = 0; j < EPB / 256; ++j) {
        int i = base + j * 256 + threadIdx.x;
        if (i < e) {
            int d = dst[i];
            int pos = atomicAdd(&lcur[d >> BSH], 1);
            packed[pos] = (unsigned)src[i] | ((unsigned)(d & ((1 << BSH) - 1)) << 16);
        }
    }
}

__global__ __launch_bounds__(512) void csr_finalize(const unsigned* __restrict__ packed,
                                                    const int* __restrict__ bbase,
                                                    int* __restrict__ rowptr,
                                                    int* __restrict__ csr_src) {
    int b = blockIdx.x;
    int s0 = bbase[b], s1 = bbase[b + 1];
    int cnt = s1 - s0;
    __shared__ int ncnt[256];
    __shared__ int ncur[256];
    __shared__ int wsum[4];
    if (threadIdx.x < 256) ncnt[threadIdx.x] = 0;
    __syncthreads();
    for (int i = threadIdx.x; i < cnt; i += 512)
        atomicAdd(&ncnt[packed[s0 + i] >> 16], 1);
    __syncthreads();
    int lane = threadIdx.x & 63, w = threadIdx.x >> 6;
    int v = 0, inc = 0;
    if (threadIdx.x < 256) {
        v = ncnt[threadIdx.x]; inc = v;
#pragma unroll
        for (int off = 1; off < 64; off <<= 1) {
            int t = __shfl_up(inc, off);
            if (lane >= off) inc += t;
        }
        if (lane == 63) wsum[w] = inc;
    }
    __syncthreads();
    if (threadIdx.x < 256) {
        int woff = 0;
#pragma unroll
        for (int k = 0; k < 3; ++k) if (k < w) woff += wsum[k];
        int excl = woff + inc - v;
        int node = (b << BSH) + threadIdx.x;
        if (node < N_NODES) rowptr[node] = s0 + excl;
        ncur[threadIdx.x] = s0 + excl;
    }
    __syncthreads();
    for (int i = threadIdx.x; i < cnt; i += 512) {
        unsigned p = packed[s0 + i];
        int pos = atomicAdd(&ncur[p >> 16], 1);
        csr_src[pos] = (int)(p & 0xFFFFu);
    }
}

// ================= register-tiled GEMM + fused alpha =================
// block = 256 threads computes 64 rows x C cols; thread = 4 rows x (C/16) cols.

template<int K, int C>
__global__ __launch_bounds__(256) void gemm_alpha(
        const float* __restrict__ in, const float* __restrict__ W,
        const float* __restrict__ a_src, const float* __restrict__ a_dst,
        float* __restrict__ h, float* __restrict__ as_, float* __restrict__ ad_, int n)
{
    constexpr int CPT = C / 16;           // 4 (C=64) or 1 (C=16)
    constexpr int KP = K + 4;             // pad: 16B-aligned, 2-way bank alias (free)
    __shared__ float sx[64][KP];
    __shared__ float sW[K * C];
    int row0 = blockIdx.x * 64;
    int nvalid = n - row0;                // rows valid in this block (may be <64)

    for (int idx = threadIdx.x; idx < 64 * K / 4; idx += 256) {
        int r = idx / (K / 4), kc = idx % (K / 4);
        float4 v = {0, 0, 0, 0};
        if (r < nvalid) v = *(const float4*)&in[(size_t)(row0 + r) * K + kc * 4];
        *(float4*)&sx[r][kc * 4] = v;
    }
    for (int idx = threadIdx.x; idx < K * C / 4; idx += 256)
        *(float4*)&sW[idx * 4] = *(const float4*)&W[idx * 4];
    __syncthreads();

    int g  = threadIdx.x >> 4;            // row group 0..15
    int ci = threadIdx.x & 15;            // col group
    int r0 = g * 4;
    int c0 = ci * CPT;

    if constexpr (CPT == 4) {
        float4 acc0 = {0,0,0,0}, acc1 = {0,0,0,0}, acc2 = {0,0,0,0}, acc3 = {0,0,0,0};
        for (int k = 0; k < K; k += 4) {
            float4 w0 = *(const float4*)&sW[(k + 0) * C + c0];
            float4 w1 = *(const float4*)&sW[(k + 1) * C + c0];
            float4 w2 = *(const float4*)&sW[(k + 2) * C + c0];
            float4 w3 = *(const float4*)&sW[(k + 3) * C + c0];
            float4 x0 = *(const float4*)&sx[r0 + 0][k];
            float4 x1 = *(const float4*)&sx[r0 + 1][k];
            float4 x2 = *(const float4*)&sx[r0 + 2][k];
            float4 x3 = *(const float4*)&sx[r0 + 3][k];
#define STEP(A, X) \
            A.x = fmaf(X.x, w0.x, A.x); A.y = fmaf(X.x, w0.y, A.y); \
            A.z = fmaf(X.x, w0.z, A.z); A.w = fmaf(X.x, w0.w, A.w); \
            A.x = fmaf(X.y, w1.x, A.x); A.y = fmaf(X.y, w1.y, A.y); \
            A.z = fmaf(X.y, w1.z, A.z); A.w = fmaf(X.y, w1.w, A.w); \
            A.x = fmaf(X.z, w2.x, A.x); A.y = fmaf(X.z, w2.y, A.y); \
            A.z = fmaf(X.z, w2.z, A.z); A.w = fmaf(X.z, w2.w, A.w); \
            A.x = fmaf(X.w, w3.x, A.x); A.y = fmaf(X.w, w3.y, A.y); \
            A.z = fmaf(X.w, w3.z, A.z); A.w = fmaf(X.w, w3.w, A.w);
            STEP(acc0, x0) STEP(acc1, x1) STEP(acc2, x2) STEP(acc3, x3)
#undef STEP
        }
        // store h (16 lanes x 16B = 256B contiguous per row)
        if (r0 + 0 < nvalid) *(float4*)&h[(size_t)(row0 + r0 + 0) * C + c0] = acc0;
        if (r0 + 1 < nvalid) *(float4*)&h[(size_t)(row0 + r0 + 1) * C + c0] = acc1;
        if (r0 + 2 < nvalid) *(float4*)&h[(size_t)(row0 + r0 + 2) * C + c0] = acc2;
        if (r0 + 3 < nvalid) *(float4*)&h[(size_t)(row0 + r0 + 3) * C + c0] = acc3;
        // fused alpha: per-thread partial dot, reduce across 16-lane col group
        float4 asv = *(const float4*)&a_src[c0];
        float4 adv = *(const float4*)&a_dst[c0];
        float vs0 = acc0.x*asv.x + acc0.y*asv.y + acc0.z*asv.z + acc0.w*asv.w;
        float vs1 = acc1.x*asv.x + acc1.y*asv.y + acc1.z*asv.z + acc1.w*asv.w;
        float vs2 = acc2.x*asv.x + acc2.y*asv.y + acc2.z*asv.z + acc2.w*asv.w;
        float vs3 = acc3.x*asv.x + acc3.y*asv.y + acc3.z*asv.z + acc3.w*asv.w;
        float vd0 = acc0.x*adv.x + acc0.y*adv.y + acc0.z*adv.z + acc0.w*adv.w;
        float vd1 = acc1.x*adv.x + acc1.y*adv.y + acc1.z*adv.z + acc1.w*adv.w;
        float vd2 = acc2.x*adv.x + acc2.y*adv.y + acc2.z*adv.z + acc2.w*adv.w;
        float vd3 = acc3.x*adv.x + acc3.y*adv.y + acc3.z*adv.z + acc3.w*adv.w;
#pragma unroll
        for (int off = 1; off < 16; off <<= 1) {
            vs0 += __shfl_xor(vs0, off); vs1 += __shfl_xor(vs1, off);
            vs2 += __shfl_xor(vs2, off); vs3 += __shfl_xor(vs3, off);
            vd0 += __shfl_xor(vd0, off); vd1 += __shfl_xor(vd1, off);
            vd2 += __shfl_xor(vd2, off); vd3 += __shfl_xor(vd3, off);
        }
        if (ci == 0) {
            if (r0 + 0 < nvalid) { as_[row0+r0+0] = vs0; ad_[row0+r0+0] = vd0; }
            if (r0 + 1 < nvalid) { as_[row0+r0+1] = vs1; ad_[row0+r0+1] = vd1; }
            if (r0 + 2 < nvalid) { as_[row0+r0+2] = vs2; ad_[row0+r0+2] = vd2; }
            if (r0 + 3 < nvalid) { as_[row0+r0+3] = vs3; ad_[row0+r0+3] = vd3; }
        }
    } else {                               // CPT == 1  (C = 16)
        float s0 = 0.f, s1 = 0.f, s2 = 0.f, s3 = 0.f;
        for (int k = 0; k < K; k += 4) {
            float w0 = sW[(k + 0) * C + c0];
            float w1 = sW[(k + 1) * C + c0];
            float w2 = sW[(k + 2) * C + c0];
            float w3 = sW[(k + 3) * C + c0];
            float4 x0 = *(const float4*)&sx[r0 + 0][k];
            float4 x1 = *(const float4*)&sx[r0 + 1][k];
            float4 x2 = *(const float4*)&sx[r0 + 2][k];
            float4 x3 = *(const float4*)&sx[r0 + 3][k];
            s0 = fmaf(x0.x,w0, fmaf(x0.y,w1, fmaf(x0.z,w2, fmaf(x0.w,w3, s0))));
            s1 = fmaf(x1.x,w0, fmaf(x1.y,w1, fmaf(x1.z,w2, fmaf(x1.w,w3, s1))));
            s2 = fmaf(x2.x,w0, fmaf(x2.y,w1, fmaf(x2.z,w2, fmaf(x2.w,w3, s2))));
            s3 = fmaf(x3.x,w0, fmaf(x3.y,w1, fmaf(x3.z,w2, fmaf(x3.w,w3, s3))));
        }
        if (r0 + 0 < nvalid) h[(size_t)(row0+r0+0) * C + c0] = s0;
        if (r0 + 1 < nvalid) h[(size_t)(row0+r0+1) * C + c0] = s1;
        if (r0 + 2 < nvalid) h[(size_t)(row0+r0+2) * C + c0] = s2;
        if (r0 + 3 < nvalid) h[(size_t)(row0+r0+3) * C + c0] = s3;
        float as0 = a_src[c0], ad0 = a_dst[c0];
        float vs0 = s0*as0, vs1 = s1*as0, vs2 = s2*as0, vs3 = s3*as0;
        float vd0 = s0*ad0, vd1 = s1*ad0, vd2 = s2*ad0, vd3 = s3*ad0;
#pragma unroll
        for (int off = 1; off < 16; off <<= 1) {
            vs0 += __shfl_xor(vs0, off); vs1 += __shfl_xor(vs1, off);
            vs2 += __shfl_xor(vs2, off); vs3 += __shfl_xor(vs3, off);
            vd0 += __shfl_xor(vd0, off); vd1 += __shfl_xor(vd1, off);
            vd2 += __shfl_xor(vd2, off); vd3 += __shfl_xor(vd3, off);
        }
        if (ci == 0) {
            if (r0 + 0 < nvalid) { as_[row0+r0+0] = vs0; ad_[row0+r0+0] = vd0; }
            if (r0 + 1 < nvalid) { as_[row0+r0+1] = vs1; ad_[row0+r0+1] = vd1; }
            if (r0 + 2 < nvalid) { as_[row0+r0+2] = vs2; ad_[row0+r0+2] = vd2; }
            if (r0 + 3 < nvalid) { as_[row0+r0+3] = vs3; ad_[row0+r0+3] = vd3; }
        }
    }
}

// ================= fused single-pass softmax + aggregation =================

__device__ __forceinline__ float leaky(float e) {
    return (e >= 0.f) ? e : 0.2f * e;
}

template<bool RELU>
__global__ __launch_bounds__(256) void agg64(
        const float* __restrict__ h, const float* __restrict__ as_, const float* __restrict__ ad_,
        const int* __restrict__ rowptr, const int* __restrict__ csr_src,
        const float* __restrict__ bias, float* __restrict__ out, int n)
{
    int node = (blockIdx.x * blockDim.x + threadIdx.x) >> 6;
    if (node >= n) return;
    int lane = threadIdx.x & 63;
    int g  = lane >> 4;
    int c4 = lane & 15;
    int start = rowptr[node], end = rowptr[node + 1];
    float adn = ad_[node];

    float4 accA = {0,0,0,0}, accB = {0,0,0,0};
    float dA = 0.f, dB = 0.f;

    int t = start + g;
    for (; t + 4 < end; t += 8) {
        int sA = csr_src[t];
        int sB = csr_src[t + 4];
        float wA = __expf(leaky(as_[sA] + adn));
        float wB = __expf(leaky(as_[sB] + adn));
        float4 hA = *(const float4*)&h[(size_t)sA * 64 + c4 * 4];
        float4 hB = *(const float4*)&h[(size_t)sB * 64 + c4 * 4];
        accA.x = fmaf(wA, hA.x, accA.x); accA.y = fmaf(wA, hA.y, accA.y);
        accA.z = fmaf(wA, hA.z, accA.z); accA.w = fmaf(wA, hA.w, accA.w);
        accB.x = fmaf(wB, hB.x, accB.x); accB.y = fmaf(wB, hB.y, accB.y);
        accB.z = fmaf(wB, hB.z, accB.z); accB.w = fmaf(wB, hB.w, accB.w);
        dA += wA; dB += wB;
    }
    if (t < end) {
        int sA = csr_src[t];
        float wA = __expf(leaky(as_[sA] + adn));
        float4 hA = *(const float4*)&h[(size_t)sA * 64 + c4 * 4];
        accA.x = fmaf(wA, hA.x, accA.x); accA.y = fmaf(wA, hA.y, accA.y);
        accA.z = fmaf(wA, hA.z, accA.z); accA.w = fmaf(wA, hA.w, accA.w);
        dA += wA;
    }
    float4 a; a.x = accA.x + accB.x; a.y = accA.y + accB.y;
    a.z = accA.z + accB.z; a.w = accA.w + accB.w;
    float d = dA + dB;
#pragma unroll
    for (int off = 16; off <= 32; off <<= 1) {
        a.x += __shfl_xor(a.x, off); a.y += __shfl_xor(a.y, off);
        a.z += __shfl_xor(a.z, off); a.w += __shfl_xor(a.w, off);
        d += __shfl_xor(d, off);
    }
    if (g == 0) {
        float inv = 1.f / (d + 1e-16f);
        float4 bv = *(const float4*)&bias[c4 * 4];
        float4 o;
        o.x = fmaf(a.x, inv, bv.x); o.y = fmaf(a.y, inv, bv.y);
        o.z = fmaf(a.z, inv, bv.z); o.w = fmaf(a.w, inv, bv.w);
        if (RELU) {
            o.x = fmaxf(o.x, 0.f); o.y = fmaxf(o.y, 0.f);
            o.z = fmaxf(o.z, 0.f); o.w = fmaxf(o.w, 0.f);
        }
        *(float4*)&out[(size_t)node * 64 + c4 * 4] = o;
    }
}

template<bool RELU>
__global__ __launch_bounds__(256) void agg16(
        const float* __restrict__ h, const float* __restrict__ as_, const float* __restrict__ ad_,
        const int* __restrict__ rowptr, const int* __restrict__ csr_src,
        const float* __restrict__ bias, float* __restrict__ out, int n)
{
    int node = (blockIdx.x * blockDim.x + threadIdx.x) >> 6;
    if (node >= n) return;
    int lane = threadIdx.x & 63;
    int g  = lane >> 2;
    int c4 = lane & 3;
    int start = rowptr[node], end = rowptr[node + 1];
    float adn = ad_[node];

    float4 acc = {0,0,0,0};
    float d = 0.f;
    for (int t = start + g; t < end; t += 16) {
        int s = csr_src[t];
        float w = __expf(leaky(as_[s] + adn));
        float4 hv = *(const float4*)&h[(size_t)s * 16 + c4 * 4];
        acc.x = fmaf(w, hv.x, acc.x); acc.y = fmaf(w, hv.y, acc.y);
        acc.z = fmaf(w, hv.z, acc.z); acc.w = fmaf(w, hv.w, acc.w);
        d += w;
    }
#pragma unroll
    for (int off = 4; off <= 32; off <<= 1) {
        acc.x += __shfl_xor(acc.x, off); acc.y += __shfl_xor(acc.y, off);
        acc.z += __shfl_xor(acc.z, off); acc.w += __shfl_xor(acc.w, off);
        d += __shfl_xor(d, off);
    }
    if (g == 0) {
        float inv = 1.f / (d + 1e-16f);
        float4 bv = *(const float4*)&bias[c4 * 4];
        float4 o;
        o.x = fmaf(acc.x, inv, bv.x); o.y = fmaf(acc.y, inv, bv.y);
        o.z = fmaf(acc.z, inv, bv.z); o.w = fmaf(acc.w, inv, bv.w);
        if (RELU) {
            o.x = fmaxf(o.x, 0.f); o.y = fmaxf(o.y, 0.f);
            o.z = fmaxf(o.z, 0.f); o.w = fmaxf(o.w, 0.f);
        }
        *(float4*)&out[(size_t)node * 16 + c4 * 4] = o;
    }
}

// ================= launch =================

extern "C" void kernel_launch(void* const* d_in, const int* in_sizes, int n_in,
                              void* d_out, int out_size, void* d_ws, size_t ws_size,
                              hipStream_t stream) {
    const float* x   = (const float*)d_in[0];
    const int*   ei  = (const int*)  d_in[1];
    const float* W1  = (const float*)d_in[3];
    const float* as1 = (const float*)d_in[4];
    const float* ad1 = (const float*)d_in[5];
    const float* b1  = (const float*)d_in[6];
    const float* W2  = (const float*)d_in[7];
    const float* as2 = (const float*)d_in[8];
    const float* ad2 = (const float*)d_in[9];
    const float* b2  = (const float*)d_in[10];
    const float* W3  = (const float*)d_in[11];
    const float* as3 = (const float*)d_in[12];
    const float* ad3 = (const float*)d_in[13];
    const float* b3  = (const float*)d_in[14];

    const int* srcp = ei;
    const int* dstp = ei + N_EDGES;

    char* ws = (char*)d_ws;
    size_t off = 0;
    auto alloc = [&](size_t bytes) -> void* {
        void* p = ws + off;
        off = (off + bytes + 255) & ~(size_t)255;
        return p;
    };
    int*   bhist_t = (int*)  alloc((size_t)NBUCK * NBLK * sizeof(int));
    int*   bbase   = (int*)  alloc((NBUCK + 1) * sizeof(int));
    int*   rowptr  = (int*)  alloc((N_NODES + 1) * sizeof(int));
    int*   csr_src = (int*)  alloc(N_EDGES * sizeof(int));
    float* asb     = (float*)alloc(N_NODES * sizeof(float));
    float* adb     = (float*)alloc(N_NODES * sizeof(float));
    float* bufA    = (float*)alloc((size_t)N_NODES * 64 * sizeof(float));
    float* bufB    = (float*)alloc((size_t)N_NODES * 64 * sizeof(float));
    unsigned* packed = (unsigned*)bufA;   // dead before agg1 writes bufA

    bucket_hist   <<<NBLK,  256, 0, stream>>>(dstp, bhist_t, N_EDGES);
    scan_buckets  <<<1,     256, 0, stream>>>(bhist_t, bbase, rowptr);
    bucket_scatter<<<NBLK,  256, 0, stream>>>(srcp, dstp, bhist_t, packed, N_EDGES);
    csr_finalize  <<<NBUCK, 512, 0, stream>>>(packed, bbase, rowptr, csr_src);

    const int NB64 = (N_NODES + 63) / 64;   // 64-row tiles
    const int NB4  = (N_NODES + 3) / 4;     // wave per node

    // layer 1: 128 -> 64, relu
    gemm_alpha<128, 64><<<NB64, 256, 0, stream>>>(x, W1, as1, ad1, bufB, asb, adb, N_NODES);
    agg64<true><<<NB4, 256, 0, stream>>>(bufB, asb, adb, rowptr, csr_src, b1, bufA, N_NODES);

    // layer 2: 64 -> 64, relu
    gemm_alpha<64, 64><<<NB64, 256, 0, stream>>>(bufA, W2, as2, ad2, bufB, asb, adb, N_NODES);
    agg64<true><<<NB4, 256, 0, stream>>>(bufB, asb, adb, rowptr, csr_src, b2, bufA, N_NODES);

    // layer 3: 64 -> 16, no relu
    gemm_alpha<64, 16><<<NB64, 256, 0, stream>>>(bufA, W3, as3, ad3, bufB, asb, adb, N_NODES);
    agg16<false><<<NB4, 256, 0, stream>>>(bufB, asb, adb, rowptr, csr_src, b3, (float*)d_out, N_NODES);
}

// Round 6
// 227.043 us; speedup vs baseline: 3.2267x; 1.1812x over previous
//
#include <hip/hip_runtime.h>
#include <math.h>

#define N_NODES 50000
#define N_EDGES 1600000
#define BSH 8                                   // 256 nodes per bucket
#define NBUCK ((N_NODES + 255) >> BSH)          // 196
#define EPB 4096                                // edges per scatter/hist block
#define NBLK ((N_EDGES + EPB - 1) / EPB)        // 391

// ================= CSR build (atomic-free at global scope) =================

__global__ __launch_bounds__(256) void bucket_hist(const int* __restrict__ dst,
                                                   int* __restrict__ bhist_t, int e) {
    __shared__ int h[NBUCK];
    for (int i = threadIdx.x; i < NBUCK; i += 256) h[i] = 0;
    __syncthreads();
    int base = blockIdx.x * EPB;
#pragma unroll
    for (int j = 0; j < EPB / 256; ++j) {
        int i = base + j * 256 + threadIdx.x;
        if (i < e) atomicAdd(&h[dst[i] >> BSH], 1);
    }
    __syncthreads();
    for (int i = threadIdx.x; i < NBUCK; i += 256)
        bhist_t[i * NBLK + blockIdx.x] = h[i];
}

// block b: coalesced sum of column b -> btot[b]
__global__ __launch_bounds__(256) void bucket_totals(const int* __restrict__ bhist_t,
                                                     int* __restrict__ btot) {
    int b = blockIdx.x;
    const int* col = bhist_t + (size_t)b * NBLK;
    int s = 0;
    for (int i = threadIdx.x; i < NBLK; i += 256) s += col[i];
#pragma unroll
    for (int off = 1; off < 64; off <<= 1) s += __shfl_xor(s, off);
    __shared__ int red[4];
    if ((threadIdx.x & 63) == 0) red[threadIdx.x >> 6] = s;
    __syncthreads();
    if (threadIdx.x == 0)
        btot[b] = red[0] + red[1] + red[2] + red[3];
}

// 1 small block: exclusive scan over 196 bucket totals
__global__ __launch_bounds__(256) void scan_totals(const int* __restrict__ btot,
                                                   int* __restrict__ bbase,
                                                   int* __restrict__ rowptr) {
    __shared__ int s[256];
    int b = threadIdx.x;
    int v = (b < NBUCK) ? btot[b] : 0;
    s[b] = v;
    __syncthreads();
    for (int off = 1; off < 256; off <<= 1) {
        int t = (b >= off) ? s[b - off] : 0;
        __syncthreads();
        s[b] += t;
        __syncthreads();
    }
    if (b < NBUCK) bbase[b] = s[b] - v;
    if (b == NBUCK - 1) { bbase[NBUCK] = s[b]; rowptr[N_NODES] = s[b]; }
}

// one wave per bucket: exclusive scan of its column, +bbase, rewrite in place
__global__ __launch_bounds__(64) void rewrite_offsets(int* __restrict__ bhist_t,
                                                      const int* __restrict__ bbase) {
    int b = blockIdx.x;
    int* col = bhist_t + (size_t)b * NBLK;
    __shared__ int buf[NBLK];
    for (int i = threadIdx.x; i < NBLK; i += 64) buf[i] = col[i];
    __syncthreads();
    constexpr int CH = (NBLK + 63) / 64;
    int lane = threadIdx.x;
    int lo = lane * CH;
    int hi = lo + CH; if (hi > NBLK) hi = NBLK;
    int s = 0;
    for (int i = lo; i < hi; ++i) s += buf[i];
    int inc = s;
#pragma unroll
    for (int off = 1; off < 64; off <<= 1) {
        int t = __shfl_up(inc, off);
        if (lane >= off) inc += t;
    }
    int run = bbase[b] + inc - s;                 // exclusive prefix of this chunk
    for (int i = lo; i < hi; ++i) { int c = buf[i]; col[i] = run; run += c; }
}

__global__ __launch_bounds__(256) void bucket_scatter(const int* __restrict__ src,
                                                      const int* __restrict__ dst,
                                                      const int* __restrict__ bhist_t,
                                                      unsigned* __restrict__ packed, int e) {
    __shared__ int lcur[NBUCK];
    int r = blockIdx.x;
    for (int i = threadIdx.x; i < NBUCK; i += 256)
        lcur[i] = bhist_t[i * NBLK + r];
    __syncthreads();
    int base = r * EPB;
#pragma unroll
    for (int j = 0; j < EPB / 256; ++j) {
        int i = base + j * 256 + threadIdx.x;
        if (i < e) {
            int d = dst[i];
            int pos = atomicAdd(&lcur[d >> BSH], 1);
            packed[pos] = (unsigned)src[i] | ((unsigned)(d & ((1 << BSH) - 1)) << 16);
        }
    }
}

__global__ __launch_bounds__(512) void csr_finalize(const unsigned* __restrict__ packed,
                                                    const int* __restrict__ bbase,
                                                    int* __restrict__ rowptr,
                                                    int* __restrict__ csr_src) {
    int b = blockIdx.x;
    int s0 = bbase[b], s1 = bbase[b + 1];
    int cnt = s1 - s0;
    __shared__ int ncnt[256];
    __shared__ int ncur[256];
    __shared__ int wsum[4];
    if (threadIdx.x < 256) ncnt[threadIdx.x] = 0;
    __syncthreads();
    for (int i = threadIdx.x; i < cnt; i += 512)
        atomicAdd(&ncnt[packed[s0 + i] >> 16], 1);
    __syncthreads();
    int lane = threadIdx.x & 63, w = threadIdx.x >> 6;
    int v = 0, inc = 0;
    if (threadIdx.x < 256) {
        v = ncnt[threadIdx.x]; inc = v;
#pragma unroll
        for (int off = 1; off < 64; off <<= 1) {
            int t = __shfl_up(inc, off);
            if (lane >= off) inc += t;
        }
        if (lane == 63) wsum[w] = inc;
    }
    __syncthreads();
    if (threadIdx.x < 256) {
        int woff = 0;
#pragma unroll
        for (int k = 0; k < 3; ++k) if (k < w) woff += wsum[k];
        int excl = woff + inc - v;
        int node = (b << BSH) + threadIdx.x;
        if (node < N_NODES) rowptr[node] = s0 + excl;
        ncur[threadIdx.x] = s0 + excl;
    }
    __syncthreads();
    for (int i = threadIdx.x; i < cnt; i += 512) {
        unsigned p = packed[s0 + i];
        int pos = atomicAdd(&ncur[p >> 16], 1);
        csr_src[pos] = (int)(p & 0xFFFFu);
    }
}

// ================= register-tiled GEMM + fused alpha =================
// block = 256 threads computes 64 rows x C cols; thread = 4 rows x (C/16) cols.

template<int K, int C>
__global__ __launch_bounds__(256) void gemm_alpha(
        const float* __restrict__ in, const float* __restrict__ W,
        const float* __restrict__ a_src, const float* __restrict__ a_dst,
        float* __restrict__ h, float* __restrict__ as_, float* __restrict__ ad_, int n)
{
    constexpr int CPT = C / 16;           // 4 (C=64) or 1 (C=16)
    constexpr int KP = K + 4;             // pad: 16B-aligned, 2-way bank alias (free)
    __shared__ float sx[64][KP];
    __shared__ float sW[K * C];
    int row0 = blockIdx.x * 64;
    int nvalid = n - row0;

    for (int idx = threadIdx.x; idx < 64 * K / 4; idx += 256) {
        int r = idx / (K / 4), kc = idx % (K / 4);
        float4 v = {0, 0, 0, 0};
        if (r < nvalid) v = *(const float4*)&in[(size_t)(row0 + r) * K + kc * 4];
        *(float4*)&sx[r][kc * 4] = v;
    }
    for (int idx = threadIdx.x; idx < K * C / 4; idx += 256)
        *(float4*)&sW[idx * 4] = *(const float4*)&W[idx * 4];
    __syncthreads();

    int g  = threadIdx.x >> 4;
    int ci = threadIdx.x & 15;
    int r0 = g * 4;
    int c0 = ci * CPT;

    if constexpr (CPT == 4) {
        float4 acc0 = {0,0,0,0}, acc1 = {0,0,0,0}, acc2 = {0,0,0,0}, acc3 = {0,0,0,0};
        for (int k = 0; k < K; k += 4) {
            float4 w0 = *(const float4*)&sW[(k + 0) * C + c0];
            float4 w1 = *(const float4*)&sW[(k + 1) * C + c0];
            float4 w2 = *(const float4*)&sW[(k + 2) * C + c0];
            float4 w3 = *(const float4*)&sW[(k + 3) * C + c0];
            float4 x0 = *(const float4*)&sx[r0 + 0][k];
            float4 x1 = *(const float4*)&sx[r0 + 1][k];
            float4 x2 = *(const float4*)&sx[r0 + 2][k];
            float4 x3 = *(const float4*)&sx[r0 + 3][k];
#define STEP(A, X) \
            A.x = fmaf(X.x, w0.x, A.x); A.y = fmaf(X.x, w0.y, A.y); \
            A.z = fmaf(X.x, w0.z, A.z); A.w = fmaf(X.x, w0.w, A.w); \
            A.x = fmaf(X.y, w1.x, A.x); A.y = fmaf(X.y, w1.y, A.y); \
            A.z = fmaf(X.y, w1.z, A.z); A.w = fmaf(X.y, w1.w, A.w); \
            A.x = fmaf(X.z, w2.x, A.x); A.y = fmaf(X.z, w2.y, A.y); \
            A.z = fmaf(X.z, w2.z, A.z); A.w = fmaf(X.z, w2.w, A.w); \
            A.x = fmaf(X.w, w3.x, A.x); A.y = fmaf(X.w, w3.y, A.y); \
            A.z = fmaf(X.w, w3.z, A.z); A.w = fmaf(X.w, w3.w, A.w);
            STEP(acc0, x0) STEP(acc1, x1) STEP(acc2, x2) STEP(acc3, x3)
#undef STEP
        }
        if (r0 + 0 < nvalid) *(float4*)&h[(size_t)(row0 + r0 + 0) * C + c0] = acc0;
        if (r0 + 1 < nvalid) *(float4*)&h[(size_t)(row0 + r0 + 1) * C + c0] = acc1;
        if (r0 + 2 < nvalid) *(float4*)&h[(size_t)(row0 + r0 + 2) * C + c0] = acc2;
        if (r0 + 3 < nvalid) *(float4*)&h[(size_t)(row0 + r0 + 3) * C + c0] = acc3;
        float4 asv = *(const float4*)&a_src[c0];
        float4 adv = *(const float4*)&a_dst[c0];
        float vs0 = acc0.x*asv.x + acc0.y*asv.y + acc0.z*asv.z + acc0.w*asv.w;
        float vs1 = acc1.x*asv.x + acc1.y*asv.y + acc1.z*asv.z + acc1.w*asv.w;
        float vs2 = acc2.x*asv.x + acc2.y*asv.y + acc2.z*asv.z + acc2.w*asv.w;
        float vs3 = acc3.x*asv.x + acc3.y*asv.y + acc3.z*asv.z + acc3.w*asv.w;
        float vd0 = acc0.x*adv.x + acc0.y*adv.y + acc0.z*adv.z + acc0.w*adv.w;
        float vd1 = acc1.x*adv.x + acc1.y*adv.y + acc1.z*adv.z + acc1.w*adv.w;
        float vd2 = acc2.x*adv.x + acc2.y*adv.y + acc2.z*adv.z + acc2.w*adv.w;
        float vd3 = acc3.x*adv.x + acc3.y*adv.y + acc3.z*adv.z + acc3.w*adv.w;
#pragma unroll
        for (int off = 1; off < 16; off <<= 1) {
            vs0 += __shfl_xor(vs0, off); vs1 += __shfl_xor(vs1, off);
            vs2 += __shfl_xor(vs2, off); vs3 += __shfl_xor(vs3, off);
            vd0 += __shfl_xor(vd0, off); vd1 += __shfl_xor(vd1, off);
            vd2 += __shfl_xor(vd2, off); vd3 += __shfl_xor(vd3, off);
        }
        if (ci == 0) {
            if (r0 + 0 < nvalid) { as_[row0+r0+0] = vs0; ad_[row0+r0+0] = vd0; }
            if (r0 + 1 < nvalid) { as_[row0+r0+1] = vs1; ad_[row0+r0+1] = vd1; }
            if (r0 + 2 < nvalid) { as_[row0+r0+2] = vs2; ad_[row0+r0+2] = vd2; }
            if (r0 + 3 < nvalid) { as_[row0+r0+3] = vs3; ad_[row0+r0+3] = vd3; }
        }
    } else {                               // CPT == 1  (C = 16)
        float s0 = 0.f, s1 = 0.f, s2 = 0.f, s3 = 0.f;
        for (int k = 0; k < K; k += 4) {
            float w0 = sW[(k + 0) * C + c0];
            float w1 = sW[(k + 1) * C + c0];
            float w2 = sW[(k + 2) * C + c0];
            float w3 = sW[(k + 3) * C + c0];
            float4 x0 = *(const float4*)&sx[r0 + 0][k];
            float4 x1 = *(const float4*)&sx[r0 + 1][k];
            float4 x2 = *(const float4*)&sx[r0 + 2][k];
            float4 x3 = *(const float4*)&sx[r0 + 3][k];
            s0 = fmaf(x0.x,w0, fmaf(x0.y,w1, fmaf(x0.z,w2, fmaf(x0.w,w3, s0))));
            s1 = fmaf(x1.x,w0, fmaf(x1.y,w1, fmaf(x1.z,w2, fmaf(x1.w,w3, s1))));
            s2 = fmaf(x2.x,w0, fmaf(x2.y,w1, fmaf(x2.z,w2, fmaf(x2.w,w3, s2))));
            s3 = fmaf(x3.x,w0, fmaf(x3.y,w1, fmaf(x3.z,w2, fmaf(x3.w,w3, s3))));
        }
        if (r0 + 0 < nvalid) h[(size_t)(row0+r0+0) * C + c0] = s0;
        if (r0 + 1 < nvalid) h[(size_t)(row0+r0+1) * C + c0] = s1;
        if (r0 + 2 < nvalid) h[(size_t)(row0+r0+2) * C + c0] = s2;
        if (r0 + 3 < nvalid) h[(size_t)(row0+r0+3) * C + c0] = s3;
        float as0 = a_src[c0], ad0 = a_dst[c0];
        float vs0 = s0*as0, vs1 = s1*as0, vs2 = s2*as0, vs3 = s3*as0;
        float vd0 = s0*ad0, vd1 = s1*ad0, vd2 = s2*ad0, vd3 = s3*ad0;
#pragma unroll
        for (int off = 1; off < 16; off <<= 1) {
            vs0 += __shfl_xor(vs0, off); vs1 += __shfl_xor(vs1, off);
            vs2 += __shfl_xor(vs2, off); vs3 += __shfl_xor(vs3, off);
            vd0 += __shfl_xor(vd0, off); vd1 += __shfl_xor(vd1, off);
            vd2 += __shfl_xor(vd2, off); vd3 += __shfl_xor(vd3, off);
        }
        if (ci == 0) {
            if (r0 + 0 < nvalid) { as_[row0+r0+0] = vs0; ad_[row0+r0+0] = vd0; }
            if (r0 + 1 < nvalid) { as_[row0+r0+1] = vs1; ad_[row0+r0+1] = vd1; }
            if (r0 + 2 < nvalid) { as_[row0+r0+2] = vs2; ad_[row0+r0+2] = vd2; }
            if (r0 + 3 < nvalid) { as_[row0+r0+3] = vs3; ad_[row0+r0+3] = vd3; }
        }
    }
}

// ================= fused single-pass softmax + aggregation =================

__device__ __forceinline__ float leaky(float e) {
    return (e >= 0.f) ? e : 0.2f * e;
}

template<bool RELU>
__global__ __launch_bounds__(256) void agg64(
        const float* __restrict__ h, const float* __restrict__ as_, const float* __restrict__ ad_,
        const int* __restrict__ rowptr, const int* __restrict__ csr_src,
        const float* __restrict__ bias, float* __restrict__ out, int n)
{
    int node = (blockIdx.x * blockDim.x + threadIdx.x) >> 6;
    if (node >= n) return;
    int lane = threadIdx.x & 63;
    int g  = lane >> 4;
    int c4 = lane & 15;
    int start = rowptr[node], end = rowptr[node + 1];
    float adn = ad_[node];

    float4 accA = {0,0,0,0}, accB = {0,0,0,0};
    float dA = 0.f, dB = 0.f;

    int t = start + g;
    for (; t + 4 < end; t += 8) {
        int sA = csr_src[t];
        int sB = csr_src[t + 4];
        float wA = __expf(leaky(as_[sA] + adn));
        float wB = __expf(leaky(as_[sB] + adn));
        float4 hA = *(const float4*)&h[(size_t)sA * 64 + c4 * 4];
        float4 hB = *(const float4*)&h[(size_t)sB * 64 + c4 * 4];
        accA.x = fmaf(wA, hA.x, accA.x); accA.y = fmaf(wA, hA.y, accA.y);
        accA.z = fmaf(wA, hA.z, accA.z); accA.w = fmaf(wA, hA.w, accA.w);
        accB.x = fmaf(wB, hB.x, accB.x); accB.y = fmaf(wB, hB.y, accB.y);
        accB.z = fmaf(wB, hB.z, accB.z); accB.w = fmaf(wB, hB.w, accB.w);
        dA += wA; dB += wB;
    }
    if (t < end) {
        int sA = csr_src[t];
        float wA = __expf(leaky(as_[sA] + adn));
        float4 hA = *(const float4*)&h[(size_t)sA * 64 + c4 * 4];
        accA.x = fmaf(wA, hA.x, accA.x); accA.y = fmaf(wA, hA.y, accA.y);
        accA.z = fmaf(wA, hA.z, accA.z); accA.w = fmaf(wA, hA.w, accA.w);
        dA += wA;
    }
    float4 a; a.x = accA.x + accB.x; a.y = accA.y + accB.y;
    a.z = accA.z + accB.z; a.w = accA.w + accB.w;
    float d = dA + dB;
#pragma unroll
    for (int off = 16; off <= 32; off <<= 1) {
        a.x += __shfl_xor(a.x, off); a.y += __shfl_xor(a.y, off);
        a.z += __shfl_xor(a.z, off); a.w += __shfl_xor(a.w, off);
        d += __shfl_xor(d, off);
    }
    if (g == 0) {
        float inv = 1.f / (d + 1e-16f);
        float4 bv = *(const float4*)&bias[c4 * 4];
        float4 o;
        o.x = fmaf(a.x, inv, bv.x); o.y = fmaf(a.y, inv, bv.y);
        o.z = fmaf(a.z, inv, bv.z); o.w = fmaf(a.w, inv, bv.w);
        if (RELU) {
            o.x = fmaxf(o.x, 0.f); o.y = fmaxf(o.y, 0.f);
            o.z = fmaxf(o.z, 0.f); o.w = fmaxf(o.w, 0.f);
        }
        *(float4*)&out[(size_t)node * 64 + c4 * 4] = o;
    }
}

template<bool RELU>
__global__ __launch_bounds__(256) void agg16(
        const float* __restrict__ h, const float* __restrict__ as_, const float* __restrict__ ad_,
        const int* __restrict__ rowptr, const int* __restrict__ csr_src,
        const float* __restrict__ bias, float* __restrict__ out, int n)
{
    int node = (blockIdx.x * blockDim.x + threadIdx.x) >> 6;
    if (node >= n) return;
    int lane = threadIdx.x & 63;
    int g  = lane >> 2;
    int c4 = lane & 3;
    int start = rowptr[node], end = rowptr[node + 1];
    float adn = ad_[node];

    float4 acc = {0,0,0,0};
    float d = 0.f;
    for (int t = start + g; t < end; t += 16) {
        int s = csr_src[t];
        float w = __expf(leaky(as_[s] + adn));
        float4 hv = *(const float4*)&h[(size_t)s * 16 + c4 * 4];
        acc.x = fmaf(w, hv.x, acc.x); acc.y = fmaf(w, hv.y, acc.y);
        acc.z = fmaf(w, hv.z, acc.z); acc.w = fmaf(w, hv.w, acc.w);
        d += w;
    }
#pragma unroll
    for (int off = 4; off <= 32; off <<= 1) {
        acc.x += __shfl_xor(acc.x, off); acc.y += __shfl_xor(acc.y, off);
        acc.z += __shfl_xor(acc.z, off); acc.w += __shfl_xor(acc.w, off);
        d += __shfl_xor(d, off);
    }
    if (g == 0) {
        float inv = 1.f / (d + 1e-16f);
        float4 bv = *(const float4*)&bias[c4 * 4];
        float4 o;
        o.x = fmaf(acc.x, inv, bv.x); o.y = fmaf(acc.y, inv, bv.y);
        o.z = fmaf(acc.z, inv, bv.z); o.w = fmaf(acc.w, inv, bv.w);
        if (RELU) {
            o.x = fmaxf(o.x, 0.f); o.y = fmaxf(o.y, 0.f);
            o.z = fmaxf(o.z, 0.f); o.w = fmaxf(o.w, 0.f);
        }
        *(float4*)&out[(size_t)node * 16 + c4 * 4] = o;
    }
}

// ================= launch =================

extern "C" void kernel_launch(void* const* d_in, const int* in_sizes, int n_in,
                              void* d_out, int out_size, void* d_ws, size_t ws_size,
                              hipStream_t stream) {
    const float* x   = (const float*)d_in[0];
    const int*   ei  = (const int*)  d_in[1];
    const float* W1  = (const float*)d_in[3];
    const float* as1 = (const float*)d_in[4];
    const float* ad1 = (const float*)d_in[5];
    const float* b1  = (const float*)d_in[6];
    const float* W2  = (const float*)d_in[7];
    const float* as2 = (const float*)d_in[8];
    const float* ad2 = (const float*)d_in[9];
    const float* b2  = (const float*)d_in[10];
    const float* W3  = (const float*)d_in[11];
    const float* as3 = (const float*)d_in[12];
    const float* ad3 = (const float*)d_in[13];
    const float* b3  = (const float*)d_in[14];

    const int* srcp = ei;
    const int* dstp = ei + N_EDGES;

    char* ws = (char*)d_ws;
    size_t off = 0;
    auto alloc = [&](size_t bytes) -> void* {
        void* p = ws + off;
        off = (off + bytes + 255) & ~(size_t)255;
        return p;
    };
    int*   bhist_t = (int*)  alloc((size_t)NBUCK * NBLK * sizeof(int));
    int*   btot    = (int*)  alloc(NBUCK * sizeof(int));
    int*   bbase   = (int*)  alloc((NBUCK + 1) * sizeof(int));
    int*   rowptr  = (int*)  alloc((N_NODES + 1) * sizeof(int));
    int*   csr_src = (int*)  alloc(N_EDGES * sizeof(int));
    float* asb     = (float*)alloc(N_NODES * sizeof(float));
    float* adb     = (float*)alloc(N_NODES * sizeof(float));
    float* bufA    = (float*)alloc((size_t)N_NODES * 64 * sizeof(float));
    float* bufB    = (float*)alloc((size_t)N_NODES * 64 * sizeof(float));
    unsigned* packed = (unsigned*)bufA;   // dead before agg1 writes bufA

    bucket_hist    <<<NBLK,  256, 0, stream>>>(dstp, bhist_t, N_EDGES);
    bucket_totals  <<<NBUCK, 256, 0, stream>>>(bhist_t, btot);
    scan_totals    <<<1,     256, 0, stream>>>(btot, bbase, rowptr);
    rewrite_offsets<<<NBUCK, 64,  0, stream>>>(bhist_t, bbase);
    bucket_scatter <<<NBLK,  256, 0, stream>>>(srcp, dstp, bhist_t, packed, N_EDGES);
    csr_finalize   <<<NBUCK, 512, 0, stream>>>(packed, bbase, rowptr, csr_src);

    const int NB64 = (N_NODES + 63) / 64;
    const int NB4  = (N_NODES + 3) / 4;

    // layer 1: 128 -> 64, relu
    gemm_alpha<128, 64><<<NB64, 256, 0, stream>>>(x, W1, as1, ad1, bufB, asb, adb, N_NODES);
    agg64<true><<<NB4, 256, 0, stream>>>(bufB, asb, adb, rowptr, csr_src, b1, bufA, N_NODES);

    // layer 2: 64 -> 64, relu
    gemm_alpha<64, 64><<<NB64, 256, 0, stream>>>(bufA, W2, as2, ad2, bufB, asb, adb, N_NODES);
    agg64<true><<<NB4, 256, 0, stream>>>(bufB, asb, adb, rowptr, csr_src, b2, bufA, N_NODES);

    // layer 3: 64 -> 16, no relu
    gemm_alpha<64, 16><<<NB64, 256, 0, stream>>>(bufA, W3, as3, ad3, bufB, asb, adb, N_NODES);
    agg16<false><<<NB4, 256, 0, stream>>>(bufB, asb, adb, rowptr, csr_src, b3, (float*)d_out, N_NODES);
}

// Round 8
// 221.031 us; speedup vs baseline: 3.3145x; 1.0272x over previous
//
#include <hip/hip_runtime.h>
#include <math.h>

#define N_NODES 50000
#define N_EDGES 1600000
#define BSH 8                                   // 256 nodes per bucket
#define NBUCK ((N_NODES + 255) >> BSH)          // 196
#define EPB 4096                                // edges per scatter/hist block
#define NBLK ((N_EDGES + EPB - 1) / EPB)        // 391

// ================= CSR build (atomic-free at global scope) =================

__global__ __launch_bounds__(256) void bucket_hist(const int* __restrict__ dst,
                                                   int* __restrict__ bhist_t, int e) {
    __shared__ int h[NBUCK];
    for (int i = threadIdx.x; i < NBUCK; i += 256) h[i] = 0;
    __syncthreads();
    int base = blockIdx.x * EPB;
#pragma unroll
    for (int j = 0; j < EPB / 256; ++j) {
        int i = base + j * 256 + threadIdx.x;
        if (i < e) atomicAdd(&h[dst[i] >> BSH], 1);
    }
    __syncthreads();
    for (int i = threadIdx.x; i < NBUCK; i += 256)
        bhist_t[i * NBLK + blockIdx.x] = h[i];
}

__global__ __launch_bounds__(256) void bucket_totals(const int* __restrict__ bhist_t,
                                                     int* __restrict__ btot) {
    int b = blockIdx.x;
    const int* col = bhist_t + (size_t)b * NBLK;
    int s = 0;
    for (int i = threadIdx.x; i < NBLK; i += 256) s += col[i];
#pragma unroll
    for (int off = 1; off < 64; off <<= 1) s += __shfl_xor(s, off);
    __shared__ int red[4];
    if ((threadIdx.x & 63) == 0) red[threadIdx.x >> 6] = s;
    __syncthreads();
    if (threadIdx.x == 0)
        btot[b] = red[0] + red[1] + red[2] + red[3];
}

__global__ __launch_bounds__(256) void scan_totals(const int* __restrict__ btot,
                                                   int* __restrict__ bbase,
                                                   int* __restrict__ rowptr) {
    __shared__ int s[256];
    int b = threadIdx.x;
    int v = (b < NBUCK) ? btot[b] : 0;
    s[b] = v;
    __syncthreads();
    for (int off = 1; off < 256; off <<= 1) {
        int t = (b >= off) ? s[b - off] : 0;
        __syncthreads();
        s[b] += t;
        __syncthreads();
    }
    if (b < NBUCK) bbase[b] = s[b] - v;
    if (b == NBUCK - 1) { bbase[NBUCK] = s[b]; rowptr[N_NODES] = s[b]; }
}

__global__ __launch_bounds__(64) void rewrite_offsets(int* __restrict__ bhist_t,
                                                      const int* __restrict__ bbase) {
    int b = blockIdx.x;
    int* col = bhist_t + (size_t)b * NBLK;
    __shared__ int buf[NBLK];
    for (int i = threadIdx.x; i < NBLK; i += 64) buf[i] = col[i];
    __syncthreads();
    constexpr int CH = (NBLK + 63) / 64;
    int lane = threadIdx.x;
    int lo = lane * CH;
    int hi = lo + CH; if (hi > NBLK) hi = NBLK;
    int s = 0;
    for (int i = lo; i < hi; ++i) s += buf[i];
    int inc = s;
#pragma unroll
    for (int off = 1; off < 64; off <<= 1) {
        int t = __shfl_up(inc, off);
        if (lane >= off) inc += t;
    }
    int run = bbase[b] + inc - s;
    for (int i = lo; i < hi; ++i) { int c = buf[i]; col[i] = run; run += c; }
}

__global__ __launch_bounds__(256) void bucket_scatter(const int* __restrict__ src,
                                                      const int* __restrict__ dst,
                                                      const int* __restrict__ bhist_t,
                                                      unsigned* __restrict__ packed, int e) {
    __shared__ int lcur[NBUCK];
    int r = blockIdx.x;
    for (int i = threadIdx.x; i < NBUCK; i += 256)
        lcur[i] = bhist_t[i * NBLK + r];
    __syncthreads();
    int base = r * EPB;
#pragma unroll
    for (int j = 0; j < EPB / 256; ++j) {
        int i = base + j * 256 + threadIdx.x;
        if (i < e) {
            int d = dst[i];
            int pos = atomicAdd(&lcur[d >> BSH], 1);
            packed[pos] = (unsigned)src[i] | ((unsigned)(d & ((1 << BSH) - 1)) << 16);
        }
    }
}

__global__ __launch_bounds__(512) void csr_finalize(const unsigned* __restrict__ packed,
                                                    const int* __restrict__ bbase,
                                                    int* __restrict__ rowptr,
                                                    int* __restrict__ csr_src) {
    int b = blockIdx.x;
    int s0 = bbase[b], s1 = bbase[b + 1];
    int cnt = s1 - s0;
    __shared__ int ncnt[256];
    __shared__ int ncur[256];
    __shared__ int wsum[4];
    if (threadIdx.x < 256) ncnt[threadIdx.x] = 0;
    __syncthreads();
    for (int i = threadIdx.x; i < cnt; i += 512)
        atomicAdd(&ncnt[packed[s0 + i] >> 16], 1);
    __syncthreads();
    int lane = threadIdx.x & 63, w = threadIdx.x >> 6;
    int v = 0, inc = 0;
    if (threadIdx.x < 256) {
        v = ncnt[threadIdx.x]; inc = v;
#pragma unroll
        for (int off = 1; off < 64; off <<= 1) {
            int t = __shfl_up(inc, off);
            if (lane >= off) inc += t;
        }
        if (lane == 63) wsum[w] = inc;
    }
    __syncthreads();
    if (threadIdx.x < 256) {
        int woff = 0;
#pragma unroll
        for (int k = 0; k < 3; ++k) if (k < w) woff += wsum[k];
        int excl = woff + inc - v;
        int node = (b << BSH) + threadIdx.x;
        if (node < N_NODES) rowptr[node] = s0 + excl;
        ncur[threadIdx.x] = s0 + excl;
    }
    __syncthreads();
    for (int i = threadIdx.x; i < cnt; i += 512) {
        unsigned p = packed[s0 + i];
        int pos = atomicAdd(&ncur[p >> 16], 1);
        csr_src[pos] = (int)(p & 0xFFFFu);
    }
}

// ================= register-tiled GEMM + fused alpha =================

template<int K, int C>
__global__ __launch_bounds__(256) void gemm_alpha(
        const float* __restrict__ in, const float* __restrict__ W,
        const float* __restrict__ a_src, const float* __restrict__ a_dst,
        float* __restrict__ h, float* __restrict__ as_, float* __restrict__ ad_, int n)
{
    constexpr int CPT = C / 16;
    constexpr int KP = K + 4;
    __shared__ float sx[64][KP];
    __shared__ float sW[K * C];
    int row0 = blockIdx.x * 64;
    int nvalid = n - row0;

    for (int idx = threadIdx.x; idx < 64 * K / 4; idx += 256) {
        int r = idx / (K / 4), kc = idx % (K / 4);
        float4 v = {0, 0, 0, 0};
        if (r < nvalid) v = *(const float4*)&in[(size_t)(row0 + r) * K + kc * 4];
        *(float4*)&sx[r][kc * 4] = v;
    }
    for (int idx = threadIdx.x; idx < K * C / 4; idx += 256)
        *(float4*)&sW[idx * 4] = *(const float4*)&W[idx * 4];
    __syncthreads();

    int g  = threadIdx.x >> 4;
    int ci = threadIdx.x & 15;
    int r0 = g * 4;
    int c0 = ci * CPT;

    if constexpr (CPT == 4) {
        float4 acc0 = {0,0,0,0}, acc1 = {0,0,0,0}, acc2 = {0,0,0,0}, acc3 = {0,0,0,0};
        for (int k = 0; k < K; k += 4) {
            float4 w0 = *(const float4*)&sW[(k + 0) * C + c0];
            float4 w1 = *(const float4*)&sW[(k + 1) * C + c0];
            float4 w2 = *(const float4*)&sW[(k + 2) * C + c0];
            float4 w3 = *(const float4*)&sW[(k + 3) * C + c0];
            float4 x0 = *(const float4*)&sx[r0 + 0][k];
            float4 x1 = *(const float4*)&sx[r0 + 1][k];
            float4 x2 = *(const float4*)&sx[r0 + 2][k];
            float4 x3 = *(const float4*)&sx[r0 + 3][k];
#define STEP(A, X) \
            A.x = fmaf(X.x, w0.x, A.x); A.y = fmaf(X.x, w0.y, A.y); \
            A.z = fmaf(X.x, w0.z, A.z); A.w = fmaf(X.x, w0.w, A.w); \
            A.x = fmaf(X.y, w1.x, A.x); A.y = fmaf(X.y, w1.y, A.y); \
            A.z = fmaf(X.y, w1.z, A.z); A.w = fmaf(X.y, w1.w, A.w); \
            A.x = fmaf(X.z, w2.x, A.x); A.y = fmaf(X.z, w2.y, A.y); \
            A.z = fmaf(X.z, w2.z, A.z); A.w = fmaf(X.z, w2.w, A.w); \
            A.x = fmaf(X.w, w3.x, A.x); A.y = fmaf(X.w, w3.y, A.y); \
            A.z = fmaf(X.w, w3.z, A.z); A.w = fmaf(X.w, w3.w, A.w);
            STEP(acc0, x0) STEP(acc1, x1) STEP(acc2, x2) STEP(acc3, x3)
#undef STEP
        }
        if (r0 + 0 < nvalid) *(float4*)&h[(size_t)(row0 + r0 + 0) * C + c0] = acc0;
        if (r0 + 1 < nvalid) *(float4*)&h[(size_t)(row0 + r0 + 1) * C + c0] = acc1;
        if (r0 + 2 < nvalid) *(float4*)&h[(size_t)(row0 + r0 + 2) * C + c0] = acc2;
        if (r0 + 3 < nvalid) *(float4*)&h[(size_t)(row0 + r0 + 3) * C + c0] = acc3;
        float4 asv = *(const float4*)&a_src[c0];
        float4 adv = *(const float4*)&a_dst[c0];
        float vs0 = acc0.x*asv.x + acc0.y*asv.y + acc0.z*asv.z + acc0.w*asv.w;
        float vs1 = acc1.x*asv.x + acc1.y*asv.y + acc1.z*asv.z + acc1.w*asv.w;
        float vs2 = acc2.x*asv.x + acc2.y*asv.y + acc2.z*asv.z + acc2.w*asv.w;
        float vs3 = acc3.x*asv.x + acc3.y*asv.y + acc3.z*asv.z + acc3.w*asv.w;
        float vd0 = acc0.x*adv.x + acc0.y*adv.y + acc0.z*adv.z + acc0.w*adv.w;
        float vd1 = acc1.x*adv.x + acc1.y*adv.y + acc1.z*adv.z + acc1.w*adv.w;
        float vd2 = acc2.x*adv.x + acc2.y*adv.y + acc2.z*adv.z + acc2.w*adv.w;
        float vd3 = acc3.x*adv.x + acc3.y*adv.y + acc3.z*adv.z + acc3.w*adv.w;
#pragma unroll
        for (int off = 1; off < 16; off <<= 1) {
            vs0 += __shfl_xor(vs0, off); vs1 += __shfl_xor(vs1, off);
            vs2 += __shfl_xor(vs2, off); vs3 += __shfl_xor(vs3, off);
            vd0 += __shfl_xor(vd0, off); vd1 += __shfl_xor(vd1, off);
            vd2 += __shfl_xor(vd2, off); vd3 += __shfl_xor(vd3, off);
        }
        if (ci == 0) {
            if (r0 + 0 < nvalid) { as_[row0+r0+0] = vs0; ad_[row0+r0+0] = vd0; }
            if (r0 + 1 < nvalid) { as_[row0+r0+1] = vs1; ad_[row0+r0+1] = vd1; }
            if (r0 + 2 < nvalid) { as_[row0+r0+2] = vs2; ad_[row0+r0+2] = vd2; }
            if (r0 + 3 < nvalid) { as_[row0+r0+3] = vs3; ad_[row0+r0+3] = vd3; }
        }
    } else {                               // CPT == 1  (C = 16)
        float s0 = 0.f, s1 = 0.f, s2 = 0.f, s3 = 0.f;
        for (int k = 0; k < K; k += 4) {
            float w0 = sW[(k + 0) * C + c0];
            float w1 = sW[(k + 1) * C + c0];
            float w2 = sW[(k + 2) * C + c0];
            float w3 = sW[(k + 3) * C + c0];
            float4 x0 = *(const float4*)&sx[r0 + 0][k];
            float4 x1 = *(const float4*)&sx[r0 + 1][k];
            float4 x2 = *(const float4*)&sx[r0 + 2][k];
            float4 x3 = *(const float4*)&sx[r0 + 3][k];
            s0 = fmaf(x0.x,w0, fmaf(x0.y,w1, fmaf(x0.z,w2, fmaf(x0.w,w3, s0))));
            s1 = fmaf(x1.x,w0, fmaf(x1.y,w1, fmaf(x1.z,w2, fmaf(x1.w,w3, s1))));
            s2 = fmaf(x2.x,w0, fmaf(x2.y,w1, fmaf(x2.z,w2, fmaf(x2.w,w3, s2))));
            s3 = fmaf(x3.x,w0, fmaf(x3.y,w1, fmaf(x3.z,w2, fmaf(x3.w,w3, s3))));
        }
        if (r0 + 0 < nvalid) h[(size_t)(row0+r0+0) * C + c0] = s0;
        if (r0 + 1 < nvalid) h[(size_t)(row0+r0+1) * C + c0] = s1;
        if (r0 + 2 < nvalid) h[(size_t)(row0+r0+2) * C + c0] = s2;
        if (r0 + 3 < nvalid) h[(size_t)(row0+r0+3) * C + c0] = s3;
        float as0 = a_src[c0], ad0 = a_dst[c0];
        float vs0 = s0*as0, vs1 = s1*as0, vs2 = s2*as0, vs3 = s3*as0;
        float vd0 = s0*ad0, vd1 = s1*ad0, vd2 = s2*ad0, vd3 = s3*ad0;
#pragma unroll
        for (int off = 1; off < 16; off <<= 1) {
            vs0 += __shfl_xor(vs0, off); vs1 += __shfl_xor(vs1, off);
            vs2 += __shfl_xor(vs2, off); vs3 += __shfl_xor(vs3, off);
            vd0 += __shfl_xor(vd0, off); vd1 += __shfl_xor(vd1, off);
            vd2 += __shfl_xor(vd2, off); vd3 += __shfl_xor(vd3, off);
        }
        if (ci == 0) {
            if (r0 + 0 < nvalid) { as_[row0+r0+0] = vs0; ad_[row0+r0+0] = vd0; }
            if (r0 + 1 < nvalid) { as_[row0+r0+1] = vs1; ad_[row0+r0+1] = vd1; }
            if (r0 + 2 < nvalid) { as_[row0+r0+2] = vs2; ad_[row0+r0+2] = vd2; }
            if (r0 + 3 < nvalid) { as_[row0+r0+3] = vs3; ad_[row0+r0+3] = vd3; }
        }
    }
}

// ================= fused single-pass softmax + aggregation =================
// Cooperative alpha: all 64 lanes compute exp(leaky(.)) for a 64-edge chunk
// (1 exp/edge, coalesced csr_src), consumers pull (src,alpha) via __shfl.
// CORRECTNESS RULE (CDNA): __shfl = ds_bpermute, reads from EXEC-inactive
// lanes are UNDEFINED. So every gather loop uses a bound (nvu, multiple of
// group stride) that gives ALL groups identical trip counts -> wave never
// diverges at a shfl. Out-of-range slots carry aw=0/ssrc=0 (harmless h[0]
// gather at weight 0).

__device__ __forceinline__ float leaky(float e) {
    return (e >= 0.f) ? e : 0.2f * e;
}

template<bool RELU>
__global__ __launch_bounds__(256) void agg64(
        const float* __restrict__ h, const float* __restrict__ as_, const float* __restrict__ ad_,
        const int* __restrict__ rowptr, const int* __restrict__ csr_src,
        const float* __restrict__ bias, float* __restrict__ out, int n)
{
    int node = (blockIdx.x * blockDim.x + threadIdx.x) >> 6;
    if (node >= n) return;
    int lane = threadIdx.x & 63;
    int g  = lane >> 4;       // edge group 0..3 (handles j = g+4k)
    int c4 = lane & 15;       // float4 slot within 64-ch row
    int start = rowptr[node], end = rowptr[node + 1];
    float adn = ad_[node];

    float4 acc = {0,0,0,0};
    float dsum = 0.f;

    for (int chunk = start; chunk < end; chunk += 64) {
        int e_i = chunk + lane;
        int ssrc = 0; float aw = 0.f;
        if (e_i < end) {
            ssrc = csr_src[e_i];                       // coalesced
            aw = __expf(leaky(as_[ssrc] + adn));       // 1 exp per edge
        }
        dsum += aw;                                    // denom: butterfly later
        int nv = end - chunk; if (nv > 64) nv = 64;
        int nvu = (nv + 15) & ~15;                     // uniform trips for all groups
        for (int j = g; j < nvu; j += 16) {            // all lanes active at shfl
            int   s0 = __shfl(ssrc, j),      s1 = __shfl(ssrc, j + 4);
            int   s2 = __shfl(ssrc, j + 8),  s3 = __shfl(ssrc, j + 12);
            float w0 = __shfl(aw, j),        w1 = __shfl(aw, j + 4);
            float w2 = __shfl(aw, j + 8),    w3 = __shfl(aw, j + 12);
            float4 h0 = *(const float4*)&h[(size_t)s0 * 64 + c4 * 4];
            float4 h1 = *(const float4*)&h[(size_t)s1 * 64 + c4 * 4];
            float4 h2 = *(const float4*)&h[(size_t)s2 * 64 + c4 * 4];
            float4 h3 = *(const float4*)&h[(size_t)s3 * 64 + c4 * 4];
            acc.x = fmaf(w0, h0.x, acc.x); acc.y = fmaf(w0, h0.y, acc.y);
            acc.z = fmaf(w0, h0.z, acc.z); acc.w = fmaf(w0, h0.w, acc.w);
            acc.x = fmaf(w1, h1.x, acc.x); acc.y = fmaf(w1, h1.y, acc.y);
            acc.z = fmaf(w1, h1.z, acc.z); acc.w = fmaf(w1, h1.w, acc.w);
            acc.x = fmaf(w2, h2.x, acc.x); acc.y = fmaf(w2, h2.y, acc.y);
            acc.z = fmaf(w2, h2.z, acc.z); acc.w = fmaf(w2, h2.w, acc.w);
            acc.x = fmaf(w3, h3.x, acc.x); acc.y = fmaf(w3, h3.y, acc.y);
            acc.z = fmaf(w3, h3.z, acc.z); acc.w = fmaf(w3, h3.w, acc.w);
        }
    }
    // combine the 4 edge groups (all lanes active)
#pragma unroll
    for (int off = 16; off <= 32; off <<= 1) {
        acc.x += __shfl_xor(acc.x, off); acc.y += __shfl_xor(acc.y, off);
        acc.z += __shfl_xor(acc.z, off); acc.w += __shfl_xor(acc.w, off);
    }
    // full-wave denom reduction
#pragma unroll
    for (int off = 1; off <= 32; off <<= 1) dsum += __shfl_xor(dsum, off);

    if (g == 0) {
        float inv = 1.f / (dsum + 1e-16f);
        float4 bv = *(const float4*)&bias[c4 * 4];
        float4 o;
        o.x = fmaf(acc.x, inv, bv.x); o.y = fmaf(acc.y, inv, bv.y);
        o.z = fmaf(acc.z, inv, bv.z); o.w = fmaf(acc.w, inv, bv.w);
        if (RELU) {
            o.x = fmaxf(o.x, 0.f); o.y = fmaxf(o.y, 0.f);
            o.z = fmaxf(o.z, 0.f); o.w = fmaxf(o.w, 0.f);
        }
        *(float4*)&out[(size_t)node * 64 + c4 * 4] = o;
    }
}

template<bool RELU>
__global__ __launch_bounds__(256) void agg16(
        const float* __restrict__ h, const float* __restrict__ as_, const float* __restrict__ ad_,
        const int* __restrict__ rowptr, const int* __restrict__ csr_src,
        const float* __restrict__ bias, float* __restrict__ out, int n)
{
    int node = (blockIdx.x * blockDim.x + threadIdx.x) >> 6;
    if (node >= n) return;
    int lane = threadIdx.x & 63;
    int g  = lane >> 2;       // edge group 0..15 (handles j = g+16k)
    int c4 = lane & 3;        // float4 slot within 16-ch row
    int start = rowptr[node], end = rowptr[node + 1];
    float adn = ad_[node];

    float4 acc = {0,0,0,0};
    float dsum = 0.f;

    for (int chunk = start; chunk < end; chunk += 64) {
        int e_i = chunk + lane;
        int ssrc = 0; float aw = 0.f;
        if (e_i < end) {
            ssrc = csr_src[e_i];
            aw = __expf(leaky(as_[ssrc] + adn));
        }
        dsum += aw;
        int nv = end - chunk; if (nv > 64) nv = 64;
        int nvu = (nv + 15) & ~15;                     // uniform trips (stride 16)
        for (int j = g; j < nvu; j += 16) {            // all lanes active at shfl
            int   s0 = __shfl(ssrc, j);
            float w0 = __shfl(aw, j);
            float4 h0 = *(const float4*)&h[(size_t)s0 * 16 + c4 * 4];
            acc.x = fmaf(w0, h0.x, acc.x); acc.y = fmaf(w0, h0.y, acc.y);
            acc.z = fmaf(w0, h0.z, acc.z); acc.w = fmaf(w0, h0.w, acc.w);
        }
    }
#pragma unroll
    for (int off = 4; off <= 32; off <<= 1) {
        acc.x += __shfl_xor(acc.x, off); acc.y += __shfl_xor(acc.y, off);
        acc.z += __shfl_xor(acc.z, off); acc.w += __shfl_xor(acc.w, off);
    }
#pragma unroll
    for (int off = 1; off <= 32; off <<= 1) dsum += __shfl_xor(dsum, off);

    if (g == 0) {
        float inv = 1.f / (dsum + 1e-16f);
        float4 bv = *(const float4*)&bias[c4 * 4];
        float4 o;
        o.x = fmaf(acc.x, inv, bv.x); o.y = fmaf(acc.y, inv, bv.y);
        o.z = fmaf(acc.z, inv, bv.z); o.w = fmaf(acc.w, inv, bv.w);
        if (RELU) {
            o.x = fmaxf(o.x, 0.f); o.y = fmaxf(o.y, 0.f);
            o.z = fmaxf(o.z, 0.f); o.w = fmaxf(o.w, 0.f);
        }
        *(float4*)&out[(size_t)node * 16 + c4 * 4] = o;
    }
}

// ================= launch =================

extern "C" void kernel_launch(void* const* d_in, const int* in_sizes, int n_in,
                              void* d_out, int out_size, void* d_ws, size_t ws_size,
                              hipStream_t stream) {
    const float* x   = (const float*)d_in[0];
    const int*   ei  = (const int*)  d_in[1];
    const float* W1  = (const float*)d_in[3];
    const float* as1 = (const float*)d_in[4];
    const float* ad1 = (const float*)d_in[5];
    const float* b1  = (const float*)d_in[6];
    const float* W2  = (const float*)d_in[7];
    const float* as2 = (const float*)d_in[8];
    const float* ad2 = (const float*)d_in[9];
    const float* b2  = (const float*)d_in[10];
    const float* W3  = (const float*)d_in[11];
    const float* as3 = (const float*)d_in[12];
    const float* ad3 = (const float*)d_in[13];
    const float* b3  = (const float*)d_in[14];

    const int* srcp = ei;
    const int* dstp = ei + N_EDGES;

    char* ws = (char*)d_ws;
    size_t off = 0;
    auto alloc = [&](size_t bytes) -> void* {
        void* p = ws + off;
        off = (off + bytes + 255) & ~(size_t)255;
        return p;
    };
    int*   bhist_t = (int*)  alloc((size_t)NBUCK * NBLK * sizeof(int));
    int*   btot    = (int*)  alloc(NBUCK * sizeof(int));
    int*   bbase   = (int*)  alloc((NBUCK + 1) * sizeof(int));
    int*   rowptr  = (int*)  alloc((N_NODES + 1) * sizeof(int));
    int*   csr_src = (int*)  alloc(N_EDGES * sizeof(int));
    float* asb     = (float*)alloc(N_NODES * sizeof(float));
    float* adb     = (float*)alloc(N_NODES * sizeof(float));
    float* bufA    = (float*)alloc((size_t)N_NODES * 64 * sizeof(float));
    float* bufB    = (float*)alloc((size_t)N_NODES * 64 * sizeof(float));
    unsigned* packed = (unsigned*)bufA;   // dead before agg1 writes bufA

    bucket_hist    <<<NBLK,  256, 0, stream>>>(dstp, bhist_t, N_EDGES);
    bucket_totals  <<<NBUCK, 256, 0, stream>>>(bhist_t, btot);
    scan_totals    <<<1,     256, 0, stream>>>(btot, bbase, rowptr);
    rewrite_offsets<<<NBUCK, 64,  0, stream>>>(bhist_t, bbase);
    bucket_scatter <<<NBLK,  256, 0, stream>>>(srcp, dstp, bhist_t, packed, N_EDGES);
    csr_finalize   <<<NBUCK, 512, 0, stream>>>(packed, bbase, rowptr, csr_src);

    const int NB64 = (N_NODES + 63) / 64;
    const int NB4  = (N_NODES + 3) / 4;

    // layer 1: 128 -> 64, relu
    gemm_alpha<128, 64><<<NB64, 256, 0, stream>>>(x, W1, as1, ad1, bufB, asb, adb, N_NODES);
    agg64<true><<<NB4, 256, 0, stream>>>(bufB, asb, adb, rowptr, csr_src, b1, bufA, N_NODES);

    // layer 2: 64 -> 64, relu
    gemm_alpha<64, 64><<<NB64, 256, 0, stream>>>(bufA, W2, as2, ad2, bufB, asb, adb, N_NODES);
    agg64<true><<<NB4, 256, 0, stream>>>(bufB, asb, adb, rowptr, csr_src, b2, bufA, N_NODES);

    // layer 3: 64 -> 16, no relu
    gemm_alpha<64, 16><<<NB64, 256, 0, stream>>>(bufA, W3, as3, ad3, bufB, asb, adb, N_NODES);
    agg16<false><<<NB4, 256, 0, stream>>>(bufB, asb, adb, rowptr, csr_src, b3, (float*)d_out, N_NODES);
}